// Round 7
// baseline (581.533 us; speedup 1.0000x reference)
//
#include <hip/hip_runtime.h>
#include <math.h>

#define NN 10000
#define NE 160000
#define MUL 128
#define ADIM 10
#define RADF 8
#define HID 64
#define INV_SQRT3 0.57735026918962576f
#define NB64 157           // ceil(NN/64)
#define WEDGE 32           // edges per wave-window
#define NWIN (NE/WEDGE)    // 5000 windows

typedef __attribute__((ext_vector_type(8))) short bf16x8;
typedef __attribute__((ext_vector_type(4))) float f32x4;

__device__ __forceinline__ float silu_f(float x){ return x / (1.0f + __expf(-x)); }
__device__ __forceinline__ float sigmoid_f(float x){ return 1.0f / (1.0f + __expf(-x)); }
__device__ __forceinline__ unsigned short f2b(float f){
  union{float f; unsigned u;} v; v.f=f;
  unsigned r = (v.u + 0x7fffu + ((v.u>>16)&1u))>>16;
  return (unsigned short)r;
}
__device__ __forceinline__ float b2f(unsigned short h){
  union{unsigned u; float f;} v; v.u = ((unsigned)h)<<16; return v.f;
}
__device__ __forceinline__ float b2f_lo(unsigned u){
  union{unsigned u; float f;} v; v.u = u<<16; return v.f;
}
__device__ __forceinline__ float b2f_hi(unsigned u){
  union{unsigned u; float f;} v; v.u = u & 0xffff0000u; return v.f;
}

// ---------------- per-node layer1 partials (f32) ----------------
__global__ __launch_bounds__(256) void k_nodeemb(
    const float* __restrict__ attrs, const float* __restrict__ Wc,
    float* __restrict__ srP, float* __restrict__ trP,
    float* __restrict__ sdP, float* __restrict__ tdP){
  int idx = blockIdx.x*256 + threadIdx.x;
  if (idx >= NN*64) return;
  int n = idx>>6, c = idx&63;
  float s0=0,s1=0,s2=0,s3=0;
  #pragma unroll
  for (int a=0;a<ADIM;a++){
    float x = attrs[n*ADIM+a];
    s0 += x*Wc[(0*ADIM+a)*64+c];
    s1 += x*Wc[(1*ADIM+a)*64+c];
    s2 += x*Wc[(2*ADIM+a)*64+c];
    s3 += x*Wc[(3*ADIM+a)*64+c];
  }
  srP[idx]=s0; trP[idx]=s1; sdP[idx]=s2; tdP[idx]=s3;
}

// ---------------- feat prep ----------------
__global__ __launch_bounds__(256) void k_feat_prep(
    const float* __restrict__ feats, unsigned short* __restrict__ fs16,
    unsigned short* __restrict__ fv16){
  int idx = blockIdx.x*256 + threadIdx.x;
  int n = idx >> 9, c = idx & 511;
  float v = feats[idx];
  if (c < 128) fs16[n*128 + c] = f2b(v);
  else {
    int q = c - 128; int u = q/3; int i = q - 3*u;
    fv16[((size_t)n*3 + i)*128 + u] = f2b(v);
  }
}

// ---------------- weight prep: transpose + bf16 cast (+ wcomb merged) ----------------
__global__ __launch_bounds__(256) void k_prep(
    const float* __restrict__ Wr2, const float* __restrict__ Wr3,
    const float* __restrict__ Wr4,
    const float* __restrict__ Wl10, const float* __restrict__ Wl11,
    const float* __restrict__ Wl20, const float* __restrict__ Wl21,
    const float* __restrict__ Wsk0, const float* __restrict__ Wup0, const float* __restrict__ Wres0,
    const float* __restrict__ Wsk1, const float* __restrict__ Wup1, const float* __restrict__ Wres1,
    const float* __restrict__ Wsrc, const float* __restrict__ Wtgt,
    const float* __restrict__ Wr1, const float* __restrict__ Wd1,
    unsigned short* __restrict__ WTr2, unsigned short* __restrict__ WTr3,
    unsigned short* __restrict__ WTr4,
    unsigned short* __restrict__ Wl10T, unsigned short* __restrict__ Wl11T,
    unsigned short* __restrict__ Wl20T, unsigned short* __restrict__ Wl21T,
    unsigned short* __restrict__ WnsT, unsigned short* __restrict__ WnvT,
    float* __restrict__ Wc){
  int idx = blockIdx.x*256 + threadIdx.x;
  if (idx < 4096){
    int j = idx; int n=j>>6, k=j&63;
    WTr2[j] = f2b(Wr2[k*64+n]);
  } else if (idx < 8192){
    int j = idx-4096; int n=j>>6, k=j&63;
    WTr3[j] = f2b(Wr3[k*64+n]);
  } else if (idx < 40960){
    int j = idx-8192; int n=j>>6, k=j&63;
    WTr4[j] = f2b(Wr4[k*512+n]);
  } else if (idx < 106496){
    int j = idx-40960; int n=j>>8, k=j&255;
    Wl10T[j] = f2b(Wl10[k*256+n]);
  } else if (idx < 139264){
    int j = idx-106496; int n=j>>8, k=j&255;
    Wl11T[j] = f2b(Wl11[k*128+n]);
  } else if (idx < 155648){
    int j = idx-139264; int n=j>>7, k=j&127;
    Wl20T[j] = f2b(Wl20[k*128+n]);
  } else if (idx < 172032){
    int j = idx-155648; int n=j>>7, k=j&127;
    Wl21T[j] = f2b(Wl21[k*128+n]);
  } else if (idx < 237568){
    int j = idx-172032; int n=j>>7, k=j&127;
    float v;
    if (n < 128)      v = Wsk0[k*128+n];
    else if (n < 256) v = Wup0[k*128+(n-128)];
    else              v = Wres0[k*256+(n-256)];
    WnsT[j] = f2b(v);
  } else if (idx < 286720){
    int j = idx-237568; int n=j>>7, k=j&127;
    float v;
    if (n < 128)      v = Wsk1[k*128+n];
    else if (n < 256) v = Wup1[k*128+(n-128)];
    else              v = Wres1[k*128+(n-256)];
    WnvT[j] = f2b(v);
  } else if (idx < 286976){
    int j = idx - 286720;      // wcomb: Wc[m][10][64]
    int m = j>>6, c = j&63;
    const float* WA = (m&1)? Wtgt : Wsrc;
    const float* WB = (m<2)? Wr1 : Wd1;
    int koff = (m&1)? 136 : 8;
    for (int a=0;a<ADIM;a++){
      float s=0.f;
      for (int k=0;k<128;k++) s += WA[a*128+k]*WB[(koff+k)*64+c];
      Wc[(m*ADIM+a)*64+c] = s;
    }
  }
}

// ---------------- K1: per-node precompute via MFMA ----------------
__global__ __launch_bounds__(256) void k_node_pre2(
    const unsigned short* __restrict__ fs16, const unsigned short* __restrict__ fv16,
    const unsigned short* __restrict__ WnsT, const unsigned short* __restrict__ WnvT,
    float* __restrict__ out_sc,
    unsigned* __restrict__ up_sp, unsigned* __restrict__ up_vp,
    float* __restrict__ res_s, float* __restrict__ res_v){
  __shared__ unsigned short fA[64][136];
  int nb = blockIdx.x*64;
  int c = blockIdx.y;
  int g, ntc;
  if (c < 4){ g=0; ntc=c; } else { g = 1 + (c-4)/3; ntc = (c-4)%3; }
  int tid = threadIdx.x;
  int w = tid>>6, l = tid&63, m0 = w*16, lr = l&15, lg = l>>4;
  for (int idx=tid; idx<64*16; idx+=256){
    int row = idx>>4, s8 = idx&15;
    int n = min(nb+row, NN-1);
    const unsigned short* src = (g==0) ? &fs16[(size_t)n*128 + s8*8]
                                       : &fv16[((size_t)n*3 + (g-1))*128 + s8*8];
    *(uint4*)&fA[row][s8*8] = *(const uint4*)src;
  }
  __syncthreads();
  const unsigned short* WT = ((g==0)? WnsT : WnvT) + (size_t)ntc*128*128;
  f32x4 acc[8];
  #pragma unroll
  for (int t=0;t<8;t++) acc[t]=(f32x4)(0.f);
  #pragma unroll
  for (int kb=0;kb<4;kb++){
    bf16x8 a = *(const bf16x8*)&fA[m0+lr][kb*32 + lg*8];
    #pragma unroll
    for (int t=0;t<8;t++){
      bf16x8 b = *(const bf16x8*)&WT[(size_t)(t*16+lr)*128 + kb*32 + lg*8];
      acc[t] = __builtin_amdgcn_mfma_f32_16x16x32_bf16(a, b, acc[t], 0,0,0);
    }
  }
  #pragma unroll
  for (int t=0;t<8;t++){
    #pragma unroll
    for (int r=0;r<4;r++){
      int col = (ntc*8+t)*16 + lr;
      int row = m0 + lg*4 + r;
      int n = nb + row;
      if (n < NN){
        float v = acc[t][r];
        if (g==0){
          if (col < 128)      out_sc[(size_t)n*512 + col] = v;
          else if (col < 256){
            int cc = col-128;
            ((unsigned short*)up_sp)[((size_t)n*64 + (cc&63))*2 + (cc>>6)] = f2b(v);
          } else              res_s[(size_t)n*256 + col-256] = v;
        } else {
          int i = g-1;
          if (col < 128)      out_sc[(size_t)n*512 + 128 + col*3 + i] = v;
          else if (col < 256){
            int cc = col-128;
            ((unsigned short*)up_vp)[(((size_t)n*3+i)*64 + (cc&63))*2 + (cc>>6)] = f2b(v);
          } else              res_v[((size_t)n*3+i)*128 + col-256] = v;
        }
      }
    }
  }
}

// ---------------- CSR build ----------------
__global__ __launch_bounds__(256) void k_deg(const int* __restrict__ eidx, int* __restrict__ deg){
  int i = blockIdx.x*256+threadIdx.x;
  if (i<NE) atomicAdd(&deg[eidx[2*i+1]],1);
}
__global__ __launch_bounds__(256) void k_scan(const int* __restrict__ deg, int* __restrict__ offsets){
  __shared__ int part[256];
  int t = threadIdx.x; int base = t*40;
  int s=0;
  for (int k=0;k<40;k++){ int idx=base+k; if (idx<NN) s+=deg[idx]; }
  part[t]=s; __syncthreads();
  if (t==0){ int run=0; for (int i=0;i<256;i++){ int v=part[i]; part[i]=run; run+=v; } }
  __syncthreads();
  int run = part[t];
  for (int k=0;k<40;k++){
    int idx=base+k;
    if (idx<=NN) offsets[idx]=run;
    if (idx<NN) run+=deg[idx];
  }
}
__global__ __launch_bounds__(256) void k_fill(const int* __restrict__ eidx, const int* __restrict__ offsets,
                                              int* __restrict__ cursor, int* __restrict__ elist){
  int i = blockIdx.x*256+threadIdx.x;
  if (i<NE){ int r = eidx[2*i+1]; int p = atomicAdd(&cursor[r],1); elist[offsets[r]+p]=i; }
}

// ---------------- K2: FUSED edge MLP + segmented gather (no atomics, no tpw buffer) ----
// One wave per 32-edge CSR window. Interior segments store msg directly; window-straddling
// segments write pbufH/pbufT partials, combined by k_fixup. Node spanning >2 windows
// handled by chain fixup. Waves fully independent (no barriers).
__global__ __launch_bounds__(256) void k_fused(
    const int* __restrict__ elist, const int* __restrict__ eidx,
    const float* __restrict__ ef, const float* __restrict__ ea,
    const float* __restrict__ srP, const float* __restrict__ trP,
    const float* __restrict__ sdP, const float* __restrict__ tdP,
    const float* __restrict__ Wr1, const float* __restrict__ Wd1, const float* __restrict__ Wd2,
    const unsigned short* __restrict__ WTr2, const unsigned short* __restrict__ WTr3,
    const unsigned short* __restrict__ WTr4,
    const int* __restrict__ offsets,
    const unsigned* __restrict__ up_sp, const unsigned* __restrict__ up_vp,
    float* __restrict__ msg_s, float* __restrict__ msg_v, float* __restrict__ density,
    float* __restrict__ pbufH, float* __restrict__ pbufT,
    float* __restrict__ pbufHd, float* __restrict__ pbufTd){
  __shared__ unsigned short shA[4][16][72];
  __shared__ unsigned short shB[4][16][132];   // layer2/3 pingpong (u16 cols) + layer4 u32 restage
  __shared__ unsigned short sef[4][WEDGE][8];  // bf16 edge feats
  __shared__ float sy[4][WEDGE][4];
  __shared__ int s_snd[4][WEDGE], s_rcv[4][WEDGE];
  int tid=threadIdx.x, w=tid>>6, l=tid&63, lr=l&15, lg=l>>4;
  int W = blockIdx.x*4 + w;
  int Wbase = W*WEDGE;
  if (l < WEDGE){
    int e = elist[Wbase + l];
    int sn = eidx[2*e], rc = eidx[2*e+1];
    s_snd[w][l]=sn; s_rcv[w][l]=rc;
    *(float4*)&sy[w][l][0] = *(const float4*)&ea[(size_t)e*4];
    float4 e0 = *(const float4*)&ef[(size_t)e*8];
    float4 e1 = *(const float4*)&ef[(size_t)e*8+4];
    unsigned short t8[8]={f2b(e0.x),f2b(e0.y),f2b(e0.z),f2b(e0.w),
                          f2b(e1.x),f2b(e1.y),f2b(e1.z),f2b(e1.w)};
    *(uint4*)&sef[w][l][0] = *(uint4*)t8;
  }
  float wr1c[8], wd1c[8];
  #pragma unroll
  for (int k=0;k<8;k++){ wr1c[k]=Wr1[k*64+l]; wd1c[k]=Wd1[k*64+l]; }
  float wd2c = Wd2[l];
  float mA0=0,mA1=0,mD0=0,mD1=0;
  float mB00=0,mB01=0,mB10=0,mB11=0,mB20=0,mB21=0;
  float mC00=0,mC01=0,mC10=0,mC11=0,mC20=0,mC21=0;
  float dAcc=0;
  unsigned* bp32 = (unsigned*)&shB[w][0][0];   // stride 66 u32 per row

  for (int sub=0; sub<2; ++sub){
    int r0 = sub*16;
    // ---- layer1 (VALU f32) + density segment walk ----
    #pragma unroll
    for (int j=0;j<16;j++){
      int rr=r0+j;
      int sn=s_snd[w][rr], rc=s_rcv[w][rr];
      float h  = srP[sn*64+l] + trP[rc*64+l];
      float hd = sdP[sn*64+l] + tdP[rc*64+l];
      uint4 ev = *(const uint4*)&sef[w][rr][0];
      float e0=b2f_lo(ev.x), e1=b2f_hi(ev.x), e2=b2f_lo(ev.y), e3=b2f_hi(ev.y);
      float e4=b2f_lo(ev.z), e5=b2f_hi(ev.z), e6=b2f_lo(ev.w), e7=b2f_hi(ev.w);
      h  += e0*wr1c[0]+e1*wr1c[1]+e2*wr1c[2]+e3*wr1c[3]+e4*wr1c[4]+e5*wr1c[5]+e6*wr1c[6]+e7*wr1c[7];
      hd += e0*wd1c[0]+e1*wd1c[1]+e2*wd1c[2]+e3*wd1c[3]+e4*wd1c[4]+e5*wd1c[5]+e6*wd1c[6]+e7*wd1c[7];
      shA[w][j][l] = f2b(silu_f(h));
      float sv = silu_f(hd)*wd2c;
      #pragma unroll
      for (int m=32;m;m>>=1) sv += __shfl_xor(sv, m);
      dAcc += 1.f - 2.f/(1.f + __expf(2.f*sv*sv));   // tanh(sv^2)
      if (rr==WEDGE-1 || s_rcv[w][rr]!=s_rcv[w][rr+1]){
        int n = s_rcv[w][rr];
        bool head = offsets[n] < Wbase;
        bool tail = offsets[n+1] > Wbase+WEDGE;
        if (l==0){
          if (head) pbufHd[W]=dAcc;
          if (tail) pbufTd[W]=dAcc;
          if (!head && !tail) density[n]=dAcc;
        }
        dAcc=0.f;
      }
    }
    // ---- layer2: shA -> shB (wave-private, no barrier) ----
    {
      f32x4 a2[4];
      #pragma unroll
      for (int nt=0;nt<4;nt++) a2[nt]=(f32x4)(0.f);
      #pragma unroll
      for (int kb=0;kb<2;kb++){
        bf16x8 a = *(const bf16x8*)&shA[w][lr][kb*32 + lg*8];
        #pragma unroll
        for (int nt=0;nt<4;nt++){
          bf16x8 b = *(const bf16x8*)&WTr2[(nt*16+lr)*64 + kb*32 + lg*8];
          a2[nt] = __builtin_amdgcn_mfma_f32_16x16x32_bf16(a, b, a2[nt], 0,0,0);
        }
      }
      #pragma unroll
      for (int nt=0;nt<4;nt++)
        #pragma unroll
        for (int r=0;r<4;r++)
          shB[w][lg*4+r][nt*16+lr] = f2b(silu_f(a2[nt][r]));
    }
    // ---- layer3: shB -> shA ----
    {
      f32x4 a3[4];
      #pragma unroll
      for (int nt=0;nt<4;nt++) a3[nt]=(f32x4)(0.f);
      #pragma unroll
      for (int kb=0;kb<2;kb++){
        bf16x8 a = *(const bf16x8*)&shB[w][lr][kb*32 + lg*8];
        #pragma unroll
        for (int nt=0;nt<4;nt++){
          bf16x8 b = *(const bf16x8*)&WTr3[(nt*16+lr)*64 + kb*32 + lg*8];
          a3[nt] = __builtin_amdgcn_mfma_f32_16x16x32_bf16(a, b, a3[nt], 0,0,0);
        }
      }
      #pragma unroll
      for (int nt=0;nt<4;nt++)
        #pragma unroll
        for (int r=0;r<4;r++)
          shA[w][lg*4+r][nt*16+lr] = f2b(silu_f(a3[nt][r]));
    }
    // ---- preload xs (packed bf16 pair per row) ----
    unsigned xs_u[16];
    #pragma unroll
    for (int j=0;j<16;j++) xs_u[j] = up_sp[(size_t)s_snd[w][r0+j]*64 + l];
    // ---- layer4 per G + immediate message accumulation ----
    #pragma unroll
    for (int G=0; G<4; G++){
      f32x4 aE[4], aO[4];
      #pragma unroll
      for (int nt=0;nt<4;nt++){ aE[nt]=(f32x4)(0.f); aO[nt]=(f32x4)(0.f); }
      #pragma unroll
      for (int kb=0;kb<2;kb++){
        bf16x8 a = *(const bf16x8*)&shA[w][lr][kb*32 + lg*8];
        #pragma unroll
        for (int nt=0;nt<4;nt++){
          bf16x8 bE = *(const bf16x8*)&WTr4[((2*G)*64+nt*16+lr)*64 + kb*32 + lg*8];
          bf16x8 bO = *(const bf16x8*)&WTr4[((2*G+1)*64+nt*16+lr)*64 + kb*32 + lg*8];
          aE[nt] = __builtin_amdgcn_mfma_f32_16x16x32_bf16(a, bE, aE[nt], 0,0,0);
          aO[nt] = __builtin_amdgcn_mfma_f32_16x16x32_bf16(a, bO, aO[nt], 0,0,0);
        }
      }
      #pragma unroll
      for (int nt=0;nt<4;nt++)
        #pragma unroll
        for (int r=0;r<4;r++){
          unsigned pv = (unsigned)f2b(aE[nt][r]) | ((unsigned)f2b(aO[nt][r])<<16);
          bp32[(lg*4+r)*66 + nt*16+lr] = pv;
        }
      #pragma unroll
      for (int j=0;j<16;j++){
        int rr=r0+j;
        unsigned pw = bp32[j*66 + l];
        float wE=b2f_lo(pw), wO=b2f_hi(pw);
        float4 ly = *(const float4*)&sy[w][rr][0];
        if (G==0){
          mA0 += wE*b2f_lo(xs_u[j])*ly.x;
          mA1 += wO*b2f_hi(xs_u[j])*ly.x;
        } else if (G==1){
          float b0=wE*b2f_lo(xs_u[j]), b1=wO*b2f_hi(xs_u[j]);
          mB00+=b0*ly.y; mB01+=b1*ly.y;
          mB10+=b0*ly.z; mB11+=b1*ly.z;
          mB20+=b0*ly.w; mB21+=b1*ly.w;
        } else {
          int sn = s_snd[w][rr];
          unsigned uv0 = up_vp[((size_t)sn*3+0)*64+l];
          unsigned uv1 = up_vp[((size_t)sn*3+1)*64+l];
          unsigned uv2 = up_vp[((size_t)sn*3+2)*64+l];
          if (G==2){
            float c0=wE*ly.x, c1=wO*ly.x;
            mC00+=c0*b2f_lo(uv0); mC01+=c1*b2f_hi(uv0);
            mC10+=c0*b2f_lo(uv1); mC11+=c1*b2f_hi(uv1);
            mC20+=c0*b2f_lo(uv2); mC21+=c1*b2f_hi(uv2);
          } else {
            float dot0 = b2f_lo(uv0)*ly.y + b2f_lo(uv1)*ly.z + b2f_lo(uv2)*ly.w;
            float dot1 = b2f_hi(uv0)*ly.y + b2f_hi(uv1)*ly.z + b2f_hi(uv2)*ly.w;
            mD0 += wE*dot0; mD1 += wO*dot1;
          }
        }
        if (rr==WEDGE-1 || s_rcv[w][rr]!=s_rcv[w][rr+1]){
          int n = s_rcv[w][rr];
          bool head = offsets[n] < Wbase;
          bool tail = offsets[n+1] > Wbase+WEDGE;
          if (G==0){
            if (head){ float* p=pbufH+(size_t)W*1024; p[l]=mA0; p[64+l]=mA1; }
            if (tail){ float* p=pbufT+(size_t)W*1024; p[l]=mA0; p[64+l]=mA1; }
            if (!head&&!tail){ float* p=msg_s+(size_t)n*256; p[l]=mA0; p[64+l]=mA1; }
            mA0=0.f; mA1=0.f;
          } else if (G==1){
            if (head){ float* q=pbufH+(size_t)W*1024+256;
              q[l]=mB00; q[64+l]=mB01; q[256+l]=mB10; q[320+l]=mB11; q[512+l]=mB20; q[576+l]=mB21; }
            if (tail){ float* q=pbufT+(size_t)W*1024+256;
              q[l]=mB00; q[64+l]=mB01; q[256+l]=mB10; q[320+l]=mB11; q[512+l]=mB20; q[576+l]=mB21; }
            if (!head&&!tail){ float* p=msg_v+(size_t)n*768;
              p[l]=mB00; p[64+l]=mB01; p[256+l]=mB10; p[320+l]=mB11; p[512+l]=mB20; p[576+l]=mB21; }
            mB00=0;mB01=0;mB10=0;mB11=0;mB20=0;mB21=0;
          } else if (G==2){
            if (head){ float* q=pbufH+(size_t)W*1024+256;
              q[128+l]=mC00; q[192+l]=mC01; q[384+l]=mC10; q[448+l]=mC11; q[640+l]=mC20; q[704+l]=mC21; }
            if (tail){ float* q=pbufT+(size_t)W*1024+256;
              q[128+l]=mC00; q[192+l]=mC01; q[384+l]=mC10; q[448+l]=mC11; q[640+l]=mC20; q[704+l]=mC21; }
            if (!head&&!tail){ float* p=msg_v+(size_t)n*768;
              p[128+l]=mC00; p[192+l]=mC01; p[384+l]=mC10; p[448+l]=mC11; p[640+l]=mC20; p[704+l]=mC21; }
            mC00=0;mC01=0;mC10=0;mC11=0;mC20=0;mC21=0;
          } else {
            float v0=mD0*INV_SQRT3, v1=mD1*INV_SQRT3;
            if (head){ float* p=pbufH+(size_t)W*1024; p[128+l]=v0; p[192+l]=v1; }
            if (tail){ float* p=pbufT+(size_t)W*1024; p[128+l]=v0; p[192+l]=v1; }
            if (!head&&!tail){ float* p=msg_s+(size_t)n*256; p[128+l]=v0; p[192+l]=v1; }
            mD0=0.f; mD1=0.f;
          }
        }
      }
    }
  }
}

// ---------------- K3: chain fixup for window-straddling nodes ----------------
__global__ __launch_bounds__(256) void k_fixup(
    const int* __restrict__ offsets,
    const float* __restrict__ pbufH, const float* __restrict__ pbufT,
    const float* __restrict__ pbufHd, const float* __restrict__ pbufTd,
    float* __restrict__ msg_s, float* __restrict__ msg_v, float* __restrict__ density){
  int n = blockIdx.x*4 + (threadIdx.x>>6);
  if (n >= NN) return;
  int l = threadIdx.x & 63;
  int s0 = offsets[n], s1 = offsets[n+1];
  if (s1 <= s0) return;
  int a = s0/WEDGE, b = (s1-1)/WEDGE;
  if (a == b) return;          // interior, already stored
  for (int c=l; c<1024; c+=64){
    float v = pbufT[(size_t)a*1024 + c];
    for (int m=a+1; m<=b; ++m) v += pbufH[(size_t)m*1024 + c];
    if (c < 256) msg_s[(size_t)n*256 + c] = v;
    else         msg_v[(size_t)n*768 + (c-256)] = v;
  }
  if (l==0){
    float dv = pbufTd[a];
    for (int m=a+1; m<=b; ++m) dv += pbufHd[m];
    density[n] = dv;
  }
}

// ---------------- K4a: lin1 for all 5 N=128 chunks. grid (NB64, 5) ----------------
__global__ __launch_bounds__(256) void k_post1(
    const float* __restrict__ msg_s, const float* __restrict__ msg_v,
    const float* __restrict__ density,
    const float* __restrict__ res_s, const float* __restrict__ res_v,
    const unsigned short* __restrict__ Wl10T, const unsigned short* __restrict__ Wl11T,
    const float* __restrict__ alphap, const float* __restrict__ betap,
    unsigned short* __restrict__ scal16, unsigned short* __restrict__ gate16,
    unsigned short* __restrict__ vtmp16){
  __shared__ unsigned short sm[64][264];
  __shared__ float sden[64];
  int nb = blockIdx.x*64, y = blockIdx.y;
  int tid = threadIdx.x;
  int w = tid>>6, l = tid&63, m0 = w*16, lr = l&15, lg = l>>4;
  for (int idx=tid; idx<64*32; idx+=256){
    int row = idx>>5, s8 = idx&31;
    int n = min(nb+row, NN-1);
    const float* src = (y<2)? &msg_s[(size_t)n*256 + s8*8]
                            : &msg_v[(size_t)n*768 + (y-2)*256 + s8*8];
    float4 a0 = *(const float4*)src, a1 = *(const float4*)(src+4);
    unsigned short t8[8]={f2b(a0.x),f2b(a0.y),f2b(a0.z),f2b(a0.w),
                          f2b(a1.x),f2b(a1.y),f2b(a1.z),f2b(a1.w)};
    *(uint4*)&sm[row][s8*8] = *(uint4*)t8;
  }
  if (tid < 64){
    int n = min(nb+tid, NN-1);
    sden[tid] = density[n]*betap[0] + alphap[0]*20.0f;
  }
  __syncthreads();
  const unsigned short* BT = (y<2)? (Wl10T + (size_t)y*128*256) : Wl11T;
  f32x4 acc[8];
  #pragma unroll
  for (int t=0;t<8;t++) acc[t]=(f32x4)(0.f);
  for (int kb=0;kb<8;kb++){
    bf16x8 a = *(const bf16x8*)&sm[m0+lr][kb*32 + lg*8];
    #pragma unroll
    for (int t=0;t<8;t++){
      bf16x8 b = *(const bf16x8*)&BT[(size_t)(t*16+lr)*256 + kb*32 + lg*8];
      acc[t] = __builtin_amdgcn_mfma_f32_16x16x32_bf16(a, b, acc[t], 0,0,0);
    }
  }
  #pragma unroll
  for (int t=0;t<8;t++){
    #pragma unroll
    for (int r=0;r<4;r++){
      int col = t*16+lr;
      int row = m0 + lg*4 + r;
      int n = nb + row;
      if (n < NN){
        float v = acc[t][r]/sden[row];
        if (y==0){
          v += res_s[(size_t)n*256 + col];
          scal16[(size_t)n*128 + col] = f2b(silu_f(v));
        } else if (y==1){
          v += res_s[(size_t)n*256 + 128 + col];
          gate16[(size_t)n*128 + col] = f2b(sigmoid_f(v));
        } else {
          int i = y-2;
          v += res_v[((size_t)n*3+i)*128 + col];
          vtmp16[((size_t)i*NN + n)*128 + col] = f2b(v);
        }
      }
    }
  }
}

// ---------------- K4b: lin2 for 4 output components. grid (NB64, 4) ----------------
__global__ __launch_bounds__(256) void k_post2(
    const unsigned short* __restrict__ scal16, const unsigned short* __restrict__ gate16,
    const unsigned short* __restrict__ vtmp16,
    const unsigned short* __restrict__ Wl20T, const unsigned short* __restrict__ Wl21T,
    float* __restrict__ out_msg){
  __shared__ unsigned short sA[64][136];
  int nb = blockIdx.x*64, y = blockIdx.y;
  int tid = threadIdx.x;
  int w = tid>>6, l = tid&63, m0 = w*16, lr = l&15, lg = l>>4;
  for (int idx=tid; idx<64*16; idx+=256){
    int row = idx>>4, s8 = idx&15;
    int n = min(nb+row, NN-1);
    if (y==0){
      *(uint4*)&sA[row][s8*8] = *(const uint4*)&scal16[(size_t)n*128 + s8*8];
    } else {
      int i = y-1;
      uint4 va = *(const uint4*)&vtmp16[((size_t)i*NN + n)*128 + s8*8];
      uint4 vg = *(const uint4*)&gate16[(size_t)n*128 + s8*8];
      const unsigned short* pa = (const unsigned short*)&va;
      const unsigned short* pg = (const unsigned short*)&vg;
      unsigned short o[8];
      #pragma unroll
      for (int j=0;j<8;j++) o[j] = f2b(b2f(pa[j])*b2f(pg[j]));
      *(uint4*)&sA[row][s8*8] = *(const uint4*)o;
    }
  }
  __syncthreads();
  const unsigned short* BT = (y==0)? Wl20T : Wl21T;
  f32x4 acc[8];
  #pragma unroll
  for (int t=0;t<8;t++) acc[t]=(f32x4)(0.f);
  #pragma unroll
  for (int kb=0;kb<4;kb++){
    bf16x8 a = *(const bf16x8*)&sA[m0+lr][kb*32 + lg*8];
    #pragma unroll
    for (int t=0;t<8;t++){
      bf16x8 b = *(const bf16x8*)&BT[(size_t)(t*16+lr)*128 + kb*32 + lg*8];
      acc[t] = __builtin_amdgcn_mfma_f32_16x16x32_bf16(a, b, acc[t], 0,0,0);
    }
  }
  #pragma unroll
  for (int t=0;t<8;t++){
    #pragma unroll
    for (int r=0;r<4;r++){
      int col = t*16+lr;
      int n = nb + m0 + lg*4 + r;
      if (n < NN) out_msg[(size_t)n*512 + col*4 + y] = acc[t][r];
    }
  }
}

extern "C" void kernel_launch(void* const* d_in, const int* in_sizes, int n_in,
                              void* d_out, int out_size, void* d_ws, size_t ws_size,
                              hipStream_t stream){
  (void)in_sizes; (void)n_in; (void)out_size; (void)ws_size;
  const float* attrs = (const float*)d_in[0];
  const float* feats = (const float*)d_in[1];
  const float* ea    = (const float*)d_in[2];
  const float* ef    = (const float*)d_in[3];
  const float* Wsrc  = (const float*)d_in[4];
  const float* Wtgt  = (const float*)d_in[5];
  const float* Wup0  = (const float*)d_in[6];
  const float* Wup1  = (const float*)d_in[7];
  const float* Wsk0  = (const float*)d_in[8];
  const float* Wsk1  = (const float*)d_in[9];
  const float* Wres0 = (const float*)d_in[10];
  const float* Wres1 = (const float*)d_in[11];
  const float* Wl10  = (const float*)d_in[12];
  const float* Wl11  = (const float*)d_in[13];
  const float* Wl20  = (const float*)d_in[14];
  const float* Wl21  = (const float*)d_in[15];
  const float* Wr1   = (const float*)d_in[16];
  const float* Wr2   = (const float*)d_in[17];
  const float* Wr3   = (const float*)d_in[18];
  const float* Wr4   = (const float*)d_in[19];
  const float* Wd1   = (const float*)d_in[20];
  const float* Wd2   = (const float*)d_in[21];
  const float* alphap= (const float*)d_in[22];
  const float* betap = (const float*)d_in[23];
  const int*   eidx  = (const int*)d_in[24];

  char* p = (char*)d_ws;
  auto alloc = [&](size_t bytes)->char*{ char* r=p; p += (bytes+255)&~(size_t)255; return r; };
  // msg_s32, msg_v32, density contiguous -> single memset
  float*  msg_s32 = (float*)alloc((size_t)NN*256*4);
  float*  msg_v32 = (float*)alloc((size_t)NN*768*4);
  float*  density = (float*)alloc((size_t)NN*4);
  float*  pbufH   = (float*)alloc((size_t)NWIN*1024*4);
  float*  pbufT   = (float*)alloc((size_t)NWIN*1024*4);
  float*  pbufHd  = (float*)alloc((size_t)NWIN*4);
  float*  pbufTd  = (float*)alloc((size_t)NWIN*4);
  float*  res_s   = (float*)alloc((size_t)NN*256*4);
  float*  res_v   = (float*)alloc((size_t)NN*384*4);
  unsigned* up_sp = (unsigned*)alloc((size_t)NN*64*4);
  unsigned* up_vp = (unsigned*)alloc((size_t)NN*192*4);
  unsigned short* fs16 = (unsigned short*)alloc((size_t)NN*128*2);
  unsigned short* fv16 = (unsigned short*)alloc((size_t)NN*384*2);
  float* srP = (float*)alloc((size_t)NN*64*4);
  float* trP = (float*)alloc((size_t)NN*64*4);
  float* sdP = (float*)alloc((size_t)NN*64*4);
  float* tdP = (float*)alloc((size_t)NN*64*4);
  float* Wc  = (float*)alloc(4*ADIM*64*4);
  unsigned short* gate16 = (unsigned short*)alloc((size_t)NN*128*2);
  unsigned short* WTr2 = (unsigned short*)alloc(4096*2);
  unsigned short* WTr3 = (unsigned short*)alloc(4096*2);
  unsigned short* WTr4 = (unsigned short*)alloc(32768*2);
  unsigned short* Wl10T = (unsigned short*)alloc(65536*2);
  unsigned short* Wl11T = (unsigned short*)alloc(32768*2);
  unsigned short* Wl20T = (unsigned short*)alloc(16384*2);
  unsigned short* Wl21T = (unsigned short*)alloc(16384*2);
  unsigned short* WnsT  = (unsigned short*)alloc(65536*2);
  unsigned short* WnvT  = (unsigned short*)alloc(49152*2);
  int* deg     = (int*)alloc(10240*4);
  int* cursor  = (int*)alloc(10240*4);
  int* offsets = (int*)alloc(10256*4);
  int* elist   = (int*)alloc((size_t)NE*4);

  unsigned short* scal16 = fs16;   // NN*128, fs16 dead after k_node_pre2
  unsigned short* vtmp16 = fv16;   // 3*NN*128, fv16 dead after k_node_pre2

  float* out_msg = (float*)d_out;               // NN*512
  float* out_sc  = out_msg + (size_t)NN*512;    // NN*512

  hipMemsetAsync(msg_s32, 0, (size_t)NN*(256+768+1)*4, stream);
  hipMemsetAsync(deg, 0, 2*10240*sizeof(int), stream);

  k_prep<<<1121, 256, 0, stream>>>(Wr2, Wr3, Wr4, Wl10, Wl11, Wl20, Wl21,
                                   Wsk0, Wup0, Wres0, Wsk1, Wup1, Wres1,
                                   Wsrc, Wtgt, Wr1, Wd1,
                                   WTr2, WTr3, WTr4,
                                   Wl10T, Wl11T, Wl20T, Wl21T, WnsT, WnvT, Wc);
  k_nodeemb<<<(NN*64+255)/256, 256, 0, stream>>>(attrs, Wc, srP, trP, sdP, tdP);
  k_feat_prep<<<NN*512/256, 256, 0, stream>>>(feats, fs16, fv16);
  k_node_pre2<<<dim3(NB64,13), 256, 0, stream>>>(fs16, fv16, WnsT, WnvT,
                                                 out_sc, up_sp, up_vp, res_s, res_v);
  k_deg<<<(NE+255)/256, 256, 0, stream>>>(eidx, deg);
  k_scan<<<1, 256, 0, stream>>>(deg, offsets);
  k_fill<<<(NE+255)/256, 256, 0, stream>>>(eidx, offsets, cursor, elist);

  k_fused<<<NWIN/4, 256, 0, stream>>>(elist, eidx, ef, ea,
                                      srP, trP, sdP, tdP,
                                      Wr1, Wd1, Wd2, WTr2, WTr3, WTr4,
                                      offsets, up_sp, up_vp,
                                      msg_s32, msg_v32, density,
                                      pbufH, pbufT, pbufHd, pbufTd);
  k_fixup<<<(NN+3)/4, 256, 0, stream>>>(offsets, pbufH, pbufT, pbufHd, pbufTd,
                                        msg_s32, msg_v32, density);

  k_post1<<<dim3(NB64,5), 256, 0, stream>>>(msg_s32, msg_v32, density, res_s, res_v,
                                            Wl10T, Wl11T, alphap, betap,
                                            scal16, gate16, vtmp16);
  k_post2<<<dim3(NB64,4), 256, 0, stream>>>(scal16, gate16, vtmp16,
                                            Wl20T, Wl21T, out_msg);
}

// Round 8
// 446.218 us; speedup vs baseline: 1.3032x; 1.3032x over previous
//
#include <hip/hip_runtime.h>
#include <math.h>

#define NN 10000
#define NE 160000
#define MUL 128
#define ADIM 10
#define RADF 8
#define HID 64
#define INV_SQRT3 0.57735026918962576f
#define NB64 157           // ceil(NN/64)

typedef __attribute__((ext_vector_type(8))) short bf16x8;
typedef __attribute__((ext_vector_type(4))) float f32x4;

__device__ __forceinline__ float silu_f(float x){ return x / (1.0f + __expf(-x)); }
__device__ __forceinline__ float sigmoid_f(float x){ return 1.0f / (1.0f + __expf(-x)); }
__device__ __forceinline__ unsigned short f2b(float f){
  union{float f; unsigned u;} v; v.f=f;
  unsigned r = (v.u + 0x7fffu + ((v.u>>16)&1u))>>16;
  return (unsigned short)r;
}
__device__ __forceinline__ float b2f(unsigned short h){
  union{unsigned u; float f;} v; v.u = ((unsigned)h)<<16; return v.f;
}
__device__ __forceinline__ float b2f_lo(unsigned u){
  union{unsigned u; float f;} v; v.u = u<<16; return v.f;
}
__device__ __forceinline__ float b2f_hi(unsigned u){
  union{unsigned u; float f;} v; v.u = u & 0xffff0000u; return v.f;
}

// ---------------- per-node layer1 partials, packed {rad, den} float2 ----------------
__global__ __launch_bounds__(256) void k_nodeemb(
    const float* __restrict__ attrs, const float* __restrict__ Wc,
    float* __restrict__ pA, float* __restrict__ pB){
  int idx = blockIdx.x*256 + threadIdx.x;
  if (idx >= NN*64) return;
  int n = idx>>6, c = idx&63;
  float s0=0,s1=0,s2=0,s3=0;
  #pragma unroll
  for (int a=0;a<ADIM;a++){
    float x = attrs[n*ADIM+a];
    s0 += x*Wc[(0*ADIM+a)*64+c];
    s1 += x*Wc[(1*ADIM+a)*64+c];
    s2 += x*Wc[(2*ADIM+a)*64+c];
    s3 += x*Wc[(3*ADIM+a)*64+c];
  }
  pA[(size_t)n*128 + c*2 + 0] = s0;  // src rad partial
  pA[(size_t)n*128 + c*2 + 1] = s2;  // src den partial
  pB[(size_t)n*128 + c*2 + 0] = s1;  // tgt rad partial
  pB[(size_t)n*128 + c*2 + 1] = s3;  // tgt den partial
}

// ---------------- feat prep ----------------
__global__ __launch_bounds__(256) void k_feat_prep(
    const float* __restrict__ feats, unsigned short* __restrict__ fs16,
    unsigned short* __restrict__ fv16){
  int idx = blockIdx.x*256 + threadIdx.x;
  int n = idx >> 9, c = idx & 511;
  float v = feats[idx];
  if (c < 128) fs16[n*128 + c] = f2b(v);
  else {
    int q = c - 128; int u = q/3; int i = q - 3*u;
    fv16[((size_t)n*3 + i)*128 + u] = f2b(v);
  }
}

// ---------------- weight prep: transpose + bf16 cast (+ wcomb merged) ----------------
__global__ __launch_bounds__(256) void k_prep(
    const float* __restrict__ Wr2, const float* __restrict__ Wr3,
    const float* __restrict__ Wr4,
    const float* __restrict__ Wl10, const float* __restrict__ Wl11,
    const float* __restrict__ Wl20, const float* __restrict__ Wl21,
    const float* __restrict__ Wsk0, const float* __restrict__ Wup0, const float* __restrict__ Wres0,
    const float* __restrict__ Wsk1, const float* __restrict__ Wup1, const float* __restrict__ Wres1,
    const float* __restrict__ Wsrc, const float* __restrict__ Wtgt,
    const float* __restrict__ Wr1, const float* __restrict__ Wd1,
    unsigned short* __restrict__ WTr2, unsigned short* __restrict__ WTr3,
    unsigned short* __restrict__ WTr4,
    unsigned short* __restrict__ Wl10T, unsigned short* __restrict__ Wl11T,
    unsigned short* __restrict__ Wl20T, unsigned short* __restrict__ Wl21T,
    unsigned short* __restrict__ WnsT, unsigned short* __restrict__ WnvT,
    float* __restrict__ Wc){
  int idx = blockIdx.x*256 + threadIdx.x;
  if (idx < 4096){
    int j = idx; int n=j>>6, k=j&63;
    WTr2[j] = f2b(Wr2[k*64+n]);
  } else if (idx < 8192){
    int j = idx-4096; int n=j>>6, k=j&63;
    WTr3[j] = f2b(Wr3[k*64+n]);
  } else if (idx < 40960){
    int j = idx-8192; int n=j>>6, k=j&63;
    WTr4[j] = f2b(Wr4[k*512+n]);
  } else if (idx < 106496){
    int j = idx-40960; int n=j>>8, k=j&255;
    Wl10T[j] = f2b(Wl10[k*256+n]);
  } else if (idx < 139264){
    int j = idx-106496; int n=j>>8, k=j&255;
    Wl11T[j] = f2b(Wl11[k*128+n]);
  } else if (idx < 155648){
    int j = idx-139264; int n=j>>7, k=j&127;
    Wl20T[j] = f2b(Wl20[k*128+n]);
  } else if (idx < 172032){
    int j = idx-155648; int n=j>>7, k=j&127;
    Wl21T[j] = f2b(Wl21[k*128+n]);
  } else if (idx < 237568){
    int j = idx-172032; int n=j>>7, k=j&127;
    float v;
    if (n < 128)      v = Wsk0[k*128+n];
    else if (n < 256) v = Wup0[k*128+(n-128)];
    else              v = Wres0[k*256+(n-256)];
    WnsT[j] = f2b(v);
  } else if (idx < 286720){
    int j = idx-237568; int n=j>>7, k=j&127;
    float v;
    if (n < 128)      v = Wsk1[k*128+n];
    else if (n < 256) v = Wup1[k*128+(n-128)];
    else              v = Wres1[k*128+(n-256)];
    WnvT[j] = f2b(v);
  } else if (idx < 286976){
    int j = idx - 286720;      // wcomb: Wc[m][10][64]
    int m = j>>6, c = j&63;
    const float* WA = (m&1)? Wtgt : Wsrc;
    const float* WB = (m<2)? Wr1 : Wd1;
    int koff = (m&1)? 136 : 8;
    for (int a=0;a<ADIM;a++){
      float s=0.f;
      for (int k=0;k<128;k++) s += WA[a*128+k]*WB[(koff+k)*64+c];
      Wc[(m*ADIM+a)*64+c] = s;
    }
  }
}

// ---------------- K1: per-node precompute via MFMA ----------------
// upk[n][64] uint4: halfwords {xs_lo,xs_hi, xv0_lo,xv0_hi, xv1_lo,xv1_hi, xv2_lo,xv2_hi}
__global__ __launch_bounds__(256) void k_node_pre2(
    const unsigned short* __restrict__ fs16, const unsigned short* __restrict__ fv16,
    const unsigned short* __restrict__ WnsT, const unsigned short* __restrict__ WnvT,
    float* __restrict__ out_sc,
    unsigned short* __restrict__ upk16,
    float* __restrict__ res_s, float* __restrict__ res_v){
  __shared__ unsigned short fA[64][136];
  int nb = blockIdx.x*64;
  int c = blockIdx.y;
  int g, ntc;
  if (c < 4){ g=0; ntc=c; } else { g = 1 + (c-4)/3; ntc = (c-4)%3; }
  int tid = threadIdx.x;
  int w = tid>>6, l = tid&63, m0 = w*16, lr = l&15, lg = l>>4;
  for (int idx=tid; idx<64*16; idx+=256){
    int row = idx>>4, s8 = idx&15;
    int n = min(nb+row, NN-1);
    const unsigned short* src = (g==0) ? &fs16[(size_t)n*128 + s8*8]
                                       : &fv16[((size_t)n*3 + (g-1))*128 + s8*8];
    *(uint4*)&fA[row][s8*8] = *(const uint4*)src;
  }
  __syncthreads();
  const unsigned short* WT = ((g==0)? WnsT : WnvT) + (size_t)ntc*128*128;
  f32x4 acc[8];
  #pragma unroll
  for (int t=0;t<8;t++) acc[t]=(f32x4)(0.f);
  #pragma unroll
  for (int kb=0;kb<4;kb++){
    bf16x8 a = *(const bf16x8*)&fA[m0+lr][kb*32 + lg*8];
    #pragma unroll
    for (int t=0;t<8;t++){
      bf16x8 b = *(const bf16x8*)&WT[(size_t)(t*16+lr)*128 + kb*32 + lg*8];
      acc[t] = __builtin_amdgcn_mfma_f32_16x16x32_bf16(a, b, acc[t], 0,0,0);
    }
  }
  #pragma unroll
  for (int t=0;t<8;t++){
    #pragma unroll
    for (int r=0;r<4;r++){
      int col = (ntc*8+t)*16 + lr;
      int row = m0 + lg*4 + r;
      int n = nb + row;
      if (n < NN){
        float v = acc[t][r];
        if (g==0){
          if (col < 128)      out_sc[(size_t)n*512 + col] = v;
          else if (col < 256){
            int cc = col-128;
            upk16[(size_t)n*512 + (cc&63)*8 + (cc>>6)] = f2b(v);
          } else              res_s[(size_t)n*256 + col-256] = v;
        } else {
          int i = g-1;
          if (col < 128)      out_sc[(size_t)n*512 + 128 + col*3 + i] = v;
          else if (col < 256){
            int cc = col-128;
            upk16[(size_t)n*512 + (cc&63)*8 + (1+i)*2 + (cc>>6)] = f2b(v);
          } else              res_v[((size_t)n*3+i)*128 + col-256] = v;
        }
      }
    }
  }
}

// ---------------- CSR build ----------------
__global__ __launch_bounds__(256) void k_deg(const int* __restrict__ eidx, int* __restrict__ deg){
  int i = blockIdx.x*256+threadIdx.x;
  if (i<NE) atomicAdd(&deg[eidx[2*i+1]],1);
}
__global__ __launch_bounds__(256) void k_scan(const int* __restrict__ deg, int* __restrict__ offsets){
  __shared__ int part[256];
  int t = threadIdx.x; int base = t*40;
  int s=0;
  for (int k=0;k<40;k++){ int idx=base+k; if (idx<NN) s+=deg[idx]; }
  part[t]=s; __syncthreads();
  if (t==0){ int run=0; for (int i=0;i<256;i++){ int v=part[i]; part[i]=run; run+=v; } }
  __syncthreads();
  int run = part[t];
  for (int k=0;k<40;k++){
    int idx=base+k;
    if (idx<=NN) offsets[idx]=run;
    if (idx<NN) run+=deg[idx];
  }
}
__global__ __launch_bounds__(256) void k_fill(const int* __restrict__ eidx, const int* __restrict__ offsets,
                                              int* __restrict__ cursor, int* __restrict__ elist){
  int i = blockIdx.x*256+threadIdx.x;
  if (i<NE){ int r = eidx[2*i+1]; int p = atomicAdd(&cursor[r],1); elist[offsets[r]+p]=i; }
}

// ---------------- K2: edge MLP -> tpwp [edge][lane][4 u32] (direct reg->global) ------
__global__ __launch_bounds__(256) void k_tpw(
    const int* __restrict__ elist, const int* __restrict__ eidx,
    const float* __restrict__ ef, const float* __restrict__ ea,
    const float* __restrict__ pA, const float* __restrict__ pB,
    const float* __restrict__ Wr1, const float* __restrict__ Wd1, const float* __restrict__ Wd2,
    const unsigned short* __restrict__ WTr2, const unsigned short* __restrict__ WTr3,
    const unsigned short* __restrict__ WTr4,
    const int* __restrict__ offsets, int nstart, int nend, int cap,
    unsigned* __restrict__ tpwp, float4* __restrict__ ybuf,
    int* __restrict__ sndbuf, float* __restrict__ densbuf){
  __shared__ unsigned short hA[64][72];
  __shared__ unsigned short hB[64][72];
  __shared__ float efs[64][8];
  __shared__ int s_snd[64], s_rcv[64];
  int ebase = offsets[nstart];
  int eend  = min(offsets[nend], ebase + cap);
  int i0 = ebase + blockIdx.x*64;
  if (i0 >= eend) return;
  int nrows = min(64, eend - i0);
  int tid = threadIdx.x;
  int w = tid>>6, l = tid&63, m0 = w*16, lr = l&15, lg = l>>4;
  if (tid < 64){
    int ii = min(i0 + tid, eend-1);
    int e = elist[ii];
    int sn = eidx[2*e], rc = eidx[2*e+1];
    s_snd[tid]=sn; s_rcv[tid]=rc;
    if (tid < nrows){
      int li = i0 - ebase + tid;
      sndbuf[li] = sn;
      ybuf[li] = ((const float4*)ea)[e];
    }
  }
  if (tid < 128){
    int r = tid>>1, hf = tid&1;
    int e = elist[min(i0+r, eend-1)];
    *(float4*)&efs[r][hf*4] = *(const float4*)&ef[(size_t)e*8 + hf*4];
  }
  __syncthreads();
  // ---- layer1 (VALU, f32), packed node partials ----
  {
    float wr[8], wd[8];
    #pragma unroll
    for (int k=0;k<8;k++){ wr[k]=Wr1[k*64+l]; wd[k]=Wd1[k*64+l]; }
    float wd2c = Wd2[l];
    #pragma unroll
    for (int j=0;j<16;j++){
      int r = m0+j;
      int sn = s_snd[r], rc = s_rcv[r];
      float2 av = *(const float2*)&pA[(size_t)sn*128 + l*2];
      float2 bv = *(const float2*)&pB[(size_t)rc*128 + l*2];
      float h  = av.x + bv.x;
      float hd = av.y + bv.y;
      #pragma unroll
      for (int k=0;k<8;k++){ float ek=efs[r][k]; h += ek*wr[k]; hd += ek*wd[k]; }
      hA[r][l] = f2b(silu_f(h));
      float sv = silu_f(hd)*wd2c;
      #pragma unroll
      for (int m=32;m;m>>=1) sv += __shfl_xor(sv, m);
      if (l==0 && r < nrows) densbuf[i0 - ebase + r] = tanhf(sv*sv);
    }
  }
  // ---- layer2: hA -> hB (wave-private rows, no barrier) ----
  f32x4 acc[4];
  #pragma unroll
  for (int nt=0;nt<4;nt++) acc[nt]=(f32x4)(0.f);
  #pragma unroll
  for (int kb=0;kb<2;kb++){
    bf16x8 a = *(const bf16x8*)&hA[m0+lr][kb*32 + lg*8];
    #pragma unroll
    for (int nt=0;nt<4;nt++){
      bf16x8 b = *(const bf16x8*)&WTr2[(nt*16+lr)*64 + kb*32 + lg*8];
      acc[nt] = __builtin_amdgcn_mfma_f32_16x16x32_bf16(a, b, acc[nt], 0,0,0);
    }
  }
  #pragma unroll
  for (int nt=0;nt<4;nt++)
    #pragma unroll
    for (int r=0;r<4;r++)
      hB[m0+lg*4+r][nt*16+lr] = f2b(silu_f(acc[nt][r]));
  // ---- layer3: hB -> hA ----
  #pragma unroll
  for (int nt=0;nt<4;nt++) acc[nt]=(f32x4)(0.f);
  #pragma unroll
  for (int kb=0;kb<2;kb++){
    bf16x8 a = *(const bf16x8*)&hB[m0+lr][kb*32 + lg*8];
    #pragma unroll
    for (int nt=0;nt<4;nt++){
      bf16x8 b = *(const bf16x8*)&WTr3[(nt*16+lr)*64 + kb*32 + lg*8];
      acc[nt] = __builtin_amdgcn_mfma_f32_16x16x32_bf16(a, b, acc[nt], 0,0,0);
    }
  }
  #pragma unroll
  for (int nt=0;nt<4;nt++)
    #pragma unroll
    for (int r=0;r<4;r++)
      hA[m0+lg*4+r][nt*16+lr] = f2b(silu_f(acc[nt][r]));
  // ---- layer4: direct reg->global, [edge][lane c][G] packed u32, 16B stores ----
  int erow0 = i0 - ebase;
  #pragma unroll
  for (int nt=0; nt<4; nt++){
    unsigned pvv[4][4];   // [r][G], fully unrolled -> registers
    #pragma unroll
    for (int G=0; G<4; G++){
      f32x4 aE=(f32x4)(0.f), aO=(f32x4)(0.f);
      #pragma unroll
      for (int kb=0; kb<2; kb++){
        bf16x8 a  = *(const bf16x8*)&hA[m0+lr][kb*32 + lg*8];
        bf16x8 bE = *(const bf16x8*)&WTr4[((2*G)*64+nt*16+lr)*64 + kb*32 + lg*8];
        bf16x8 bO = *(const bf16x8*)&WTr4[((2*G+1)*64+nt*16+lr)*64 + kb*32 + lg*8];
        aE = __builtin_amdgcn_mfma_f32_16x16x32_bf16(a, bE, aE, 0,0,0);
        aO = __builtin_amdgcn_mfma_f32_16x16x32_bf16(a, bO, aO, 0,0,0);
      }
      #pragma unroll
      for (int r=0;r<4;r++)
        pvv[r][G] = (unsigned)f2b(aE[r]) | ((unsigned)f2b(aO[r])<<16);
    }
    #pragma unroll
    for (int r=0;r<4;r++){
      int row = m0 + lg*4 + r;
      if (row < nrows)
        *(uint4*)&tpwp[(size_t)(erow0+row)*256 + (nt*16+lr)*4] = *(uint4*)&pvv[r][0];
    }
  }
}

// ---------------- K3: CSR gather — 2 dwordx4 loads per edge ----------------
__global__ __launch_bounds__(256) void k_gather(
    const unsigned* __restrict__ tpwp, const float4* __restrict__ ybuf,
    const int* __restrict__ sndbuf, const float* __restrict__ densbuf,
    const uint4* __restrict__ upk4,
    const int* __restrict__ offsets, int nstart,
    unsigned short* __restrict__ msg_s16, unsigned short* __restrict__ msg_v16,
    float* __restrict__ density){
  int w = threadIdx.x>>6, l = threadIdx.x&63;
  int n = nstart + blockIdx.x*4 + w;
  if (n >= NN) return;
  int ebase = offsets[nstart];
  int s0 = offsets[n], s1 = offsets[n+1];
  float mA0=0,mA1=0,mD0=0,mD1=0;
  float mB00=0,mB01=0,mB10=0,mB11=0,mB20=0,mB21=0;
  float mC00=0,mC01=0,mC10=0,mC11=0,mC20=0,mC21=0;
  float dsum=0;
  #pragma unroll 2
  for (int i=s0;i<s1;++i){
    int li = i - ebase;
    int sn = sndbuf[li];
    float4 y = ybuf[li];
    dsum += densbuf[li];
    uint4 tq = *(const uint4*)&tpwp[(size_t)li*256 + l*4];
    uint4 uq = upk4[(size_t)sn*64 + l];
    float wA0=b2f_lo(tq.x), wA1=b2f_hi(tq.x);
    float wB0=b2f_lo(tq.y), wB1=b2f_hi(tq.y);
    float wC0=b2f_lo(tq.z), wC1=b2f_hi(tq.z);
    float wD0=b2f_lo(tq.w), wD1=b2f_hi(tq.w);
    float xs0=b2f_lo(uq.x), xs1=b2f_hi(uq.x);
    float xv00=b2f_lo(uq.y), xv01=b2f_hi(uq.y);
    float xv10=b2f_lo(uq.z), xv11=b2f_hi(uq.z);
    float xv20=b2f_lo(uq.w), xv21=b2f_hi(uq.w);
    mA0 += wA0*xs0*y.x; mA1 += wA1*xs1*y.x;
    float dot0 = xv00*y.y + xv10*y.z + xv20*y.w;
    float dot1 = xv01*y.y + xv11*y.z + xv21*y.w;
    mD0 += wD0*dot0; mD1 += wD1*dot1;
    float b0 = wB0*xs0, b1 = wB1*xs1;
    mB00 += b0*y.y; mB01 += b1*y.y;
    mB10 += b0*y.z; mB11 += b1*y.z;
    mB20 += b0*y.w; mB21 += b1*y.w;
    float c0 = wC0*y.x, c1 = wC1*y.x;
    mC00 += c0*xv00; mC01 += c1*xv01;
    mC10 += c0*xv10; mC11 += c1*xv11;
    mC20 += c0*xv20; mC21 += c1*xv21;
  }
  unsigned short* ms = msg_s16 + (size_t)n*256;
  ms[l]=f2b(mA0); ms[64+l]=f2b(mA1);
  ms[128+l]=f2b(mD0*INV_SQRT3); ms[192+l]=f2b(mD1*INV_SQRT3);
  unsigned short* mv = msg_v16 + (size_t)n*768;
  mv[l]=f2b(mB00);     mv[64+l]=f2b(mB01);  mv[128+l]=f2b(mC00); mv[192+l]=f2b(mC01);
  mv[256+l]=f2b(mB10); mv[320+l]=f2b(mB11); mv[384+l]=f2b(mC10); mv[448+l]=f2b(mC11);
  mv[512+l]=f2b(mB20); mv[576+l]=f2b(mB21); mv[640+l]=f2b(mC20); mv[704+l]=f2b(mC21);
  if (l==0) density[n]=dsum;
}

// ---------------- K4a: lin1 for all 5 N=128 chunks. grid (NB64, 5) ----------------
__global__ __launch_bounds__(256) void k_post1(
    const unsigned short* __restrict__ msg_s16, const unsigned short* __restrict__ msg_v16,
    const float* __restrict__ density,
    const float* __restrict__ res_s, const float* __restrict__ res_v,
    const unsigned short* __restrict__ Wl10T, const unsigned short* __restrict__ Wl11T,
    const float* __restrict__ alphap, const float* __restrict__ betap,
    unsigned short* __restrict__ scal16, unsigned short* __restrict__ gate16,
    unsigned short* __restrict__ vtmp16){
  __shared__ unsigned short sm[64][264];
  __shared__ float sden[64];
  int nb = blockIdx.x*64, y = blockIdx.y;
  int tid = threadIdx.x;
  int w = tid>>6, l = tid&63, m0 = w*16, lr = l&15, lg = l>>4;
  for (int idx=tid; idx<64*32; idx+=256){
    int row = idx>>5, s8 = idx&31;
    int n = min(nb+row, NN-1);
    const unsigned short* src = (y<2)? &msg_s16[(size_t)n*256 + s8*8]
                                     : &msg_v16[(size_t)n*768 + (y-2)*256 + s8*8];
    *(uint4*)&sm[row][s8*8] = *(const uint4*)src;
  }
  if (tid < 64){
    int n = min(nb+tid, NN-1);
    sden[tid] = density[n]*betap[0] + alphap[0]*20.0f;
  }
  __syncthreads();
  const unsigned short* BT = (y<2)? (Wl10T + (size_t)y*128*256) : Wl11T;
  f32x4 acc[8];
  #pragma unroll
  for (int t=0;t<8;t++) acc[t]=(f32x4)(0.f);
  for (int kb=0;kb<8;kb++){
    bf16x8 a = *(const bf16x8*)&sm[m0+lr][kb*32 + lg*8];
    #pragma unroll
    for (int t=0;t<8;t++){
      bf16x8 b = *(const bf16x8*)&BT[(size_t)(t*16+lr)*256 + kb*32 + lg*8];
      acc[t] = __builtin_amdgcn_mfma_f32_16x16x32_bf16(a, b, acc[t], 0,0,0);
    }
  }
  #pragma unroll
  for (int t=0;t<8;t++){
    #pragma unroll
    for (int r=0;r<4;r++){
      int col = t*16+lr;
      int row = m0 + lg*4 + r;
      int n = nb + row;
      if (n < NN){
        float v = acc[t][r]/sden[row];
        if (y==0){
          v += res_s[(size_t)n*256 + col];
          scal16[(size_t)n*128 + col] = f2b(silu_f(v));
        } else if (y==1){
          v += res_s[(size_t)n*256 + 128 + col];
          gate16[(size_t)n*128 + col] = f2b(sigmoid_f(v));
        } else {
          int i = y-2;
          v += res_v[((size_t)n*3+i)*128 + col];
          vtmp16[((size_t)i*NN + n)*128 + col] = f2b(v);
        }
      }
    }
  }
}

// ---------------- K4b: lin2 for 4 output components. grid (NB64, 4) ----------------
__global__ __launch_bounds__(256) void k_post2(
    const unsigned short* __restrict__ scal16, const unsigned short* __restrict__ gate16,
    const unsigned short* __restrict__ vtmp16,
    const unsigned short* __restrict__ Wl20T, const unsigned short* __restrict__ Wl21T,
    float* __restrict__ out_msg){
  __shared__ unsigned short sA[64][136];
  int nb = blockIdx.x*64, y = blockIdx.y;
  int tid = threadIdx.x;
  int w = tid>>6, l = tid&63, m0 = w*16, lr = l&15, lg = l>>4;
  for (int idx=tid; idx<64*16; idx+=256){
    int row = idx>>4, s8 = idx&15;
    int n = min(nb+row, NN-1);
    if (y==0){
      *(uint4*)&sA[row][s8*8] = *(const uint4*)&scal16[(size_t)n*128 + s8*8];
    } else {
      int i = y-1;
      uint4 va = *(const uint4*)&vtmp16[((size_t)i*NN + n)*128 + s8*8];
      uint4 vg = *(const uint4*)&gate16[(size_t)n*128 + s8*8];
      const unsigned short* pa = (const unsigned short*)&va;
      const unsigned short* pg = (const unsigned short*)&vg;
      unsigned short o[8];
      #pragma unroll
      for (int j=0;j<8;j++) o[j] = f2b(b2f(pa[j])*b2f(pg[j]));
      *(uint4*)&sA[row][s8*8] = *(const uint4*)o;
    }
  }
  __syncthreads();
  const unsigned short* BT = (y==0)? Wl20T : Wl21T;
  f32x4 acc[8];
  #pragma unroll
  for (int t=0;t<8;t++) acc[t]=(f32x4)(0.f);
  #pragma unroll
  for (int kb=0;kb<4;kb++){
    bf16x8 a = *(const bf16x8*)&sA[m0+lr][kb*32 + lg*8];
    #pragma unroll
    for (int t=0;t<8;t++){
      bf16x8 b = *(const bf16x8*)&BT[(size_t)(t*16+lr)*128 + kb*32 + lg*8];
      acc[t] = __builtin_amdgcn_mfma_f32_16x16x32_bf16(a, b, acc[t], 0,0,0);
    }
  }
  #pragma unroll
  for (int t=0;t<8;t++){
    #pragma unroll
    for (int r=0;r<4;r++){
      int col = t*16+lr;
      int n = nb + m0 + lg*4 + r;
      if (n < NN) out_msg[(size_t)n*512 + col*4 + y] = acc[t][r];
    }
  }
}

extern "C" void kernel_launch(void* const* d_in, const int* in_sizes, int n_in,
                              void* d_out, int out_size, void* d_ws, size_t ws_size,
                              hipStream_t stream){
  (void)in_sizes; (void)n_in; (void)out_size;
  const float* attrs = (const float*)d_in[0];
  const float* feats = (const float*)d_in[1];
  const float* ea    = (const float*)d_in[2];
  const float* ef    = (const float*)d_in[3];
  const float* Wsrc  = (const float*)d_in[4];
  const float* Wtgt  = (const float*)d_in[5];
  const float* Wup0  = (const float*)d_in[6];
  const float* Wup1  = (const float*)d_in[7];
  const float* Wsk0  = (const float*)d_in[8];
  const float* Wsk1  = (const float*)d_in[9];
  const float* Wres0 = (const float*)d_in[10];
  const float* Wres1 = (const float*)d_in[11];
  const float* Wl10  = (const float*)d_in[12];
  const float* Wl11  = (const float*)d_in[13];
  const float* Wl20  = (const float*)d_in[14];
  const float* Wl21  = (const float*)d_in[15];
  const float* Wr1   = (const float*)d_in[16];
  const float* Wr2   = (const float*)d_in[17];
  const float* Wr3   = (const float*)d_in[18];
  const float* Wr4   = (const float*)d_in[19];
  const float* Wd1   = (const float*)d_in[20];
  const float* Wd2   = (const float*)d_in[21];
  const float* alphap= (const float*)d_in[22];
  const float* betap = (const float*)d_in[23];
  const int*   eidx  = (const int*)d_in[24];

  // fixed (non-cap) bytes estimate + 256B slack per buffer
  const size_t fixed_bytes =
      (size_t)NN*(512 + 1536 + 1024 + 1536 + 4 + 1024 + 256 + 768 + 512 + 512 + 256) +
      (size_t)286976*2 + 4*ADIM*64*4 +
      (10240+10240+10256)*4 + (size_t)NE*4 + 64*256;
  // per-edge cap bytes: tpwp 1024 + ybuf 16 + densbuf 4 + sndbuf 4 = 1048
  int nchunk, npc, cap;
  if (fixed_bytes + (size_t)NE*1048 + 65536 <= ws_size){ nchunk=1; npc=NN;   cap=NE;    }
  else if (fixed_bytes + 81920ULL*1048 + 65536 <= ws_size){ nchunk=2; npc=5000; cap=81920; }
  else { nchunk=4; npc=2500; cap=44032; }

  char* p = (char*)d_ws;
  auto alloc = [&](size_t bytes)->char*{ char* r=p; p += (bytes+255)&~(size_t)255; return r; };
  unsigned* tpwp  = (unsigned*)alloc((size_t)cap*256*4);
  unsigned short* msg_s16 = (unsigned short*)alloc((size_t)NN*256*2);
  unsigned short* msg_v16 = (unsigned short*)alloc((size_t)NN*768*2);
  float*  res_s   = (float*)alloc((size_t)NN*256*4);
  float*  res_v   = (float*)alloc((size_t)NN*384*4);
  float*  density = (float*)alloc((size_t)NN*4);
  float4* ybuf    = (float4*)alloc((size_t)cap*16);
  float*  densbuf = (float*)alloc((size_t)cap*4);
  int*    sndbuf  = (int*)alloc((size_t)cap*4);
  uint4*  upk     = (uint4*)alloc((size_t)NN*64*16);
  unsigned short* fs16 = (unsigned short*)alloc((size_t)NN*128*2);
  unsigned short* fv16 = (unsigned short*)alloc((size_t)NN*384*2);
  float* pA = (float*)alloc((size_t)NN*128*4);
  float* pB = (float*)alloc((size_t)NN*128*4);
  float* Wc  = (float*)alloc(4*ADIM*64*4);
  unsigned short* gate16 = (unsigned short*)alloc((size_t)NN*128*2);
  unsigned short* WTr2 = (unsigned short*)alloc(4096*2);
  unsigned short* WTr3 = (unsigned short*)alloc(4096*2);
  unsigned short* WTr4 = (unsigned short*)alloc(32768*2);
  unsigned short* Wl10T = (unsigned short*)alloc(65536*2);
  unsigned short* Wl11T = (unsigned short*)alloc(32768*2);
  unsigned short* Wl20T = (unsigned short*)alloc(16384*2);
  unsigned short* Wl21T = (unsigned short*)alloc(16384*2);
  unsigned short* WnsT  = (unsigned short*)alloc(65536*2);
  unsigned short* WnvT  = (unsigned short*)alloc(49152*2);
  int* deg     = (int*)alloc(10240*4);
  int* cursor  = (int*)alloc(10240*4);
  int* offsets = (int*)alloc(10256*4);
  int* elist   = (int*)alloc((size_t)NE*4);

  unsigned short* scal16 = fs16;   // NN*128, fs16 dead after k_node_pre2
  unsigned short* vtmp16 = fv16;   // 3*NN*128, fv16 dead after k_node_pre2

  float* out_msg = (float*)d_out;               // NN*512
  float* out_sc  = out_msg + (size_t)NN*512;    // NN*512

  hipMemsetAsync(deg, 0, 2*10240*sizeof(int), stream);

  k_prep<<<1121, 256, 0, stream>>>(Wr2, Wr3, Wr4, Wl10, Wl11, Wl20, Wl21,
                                   Wsk0, Wup0, Wres0, Wsk1, Wup1, Wres1,
                                   Wsrc, Wtgt, Wr1, Wd1,
                                   WTr2, WTr3, WTr4,
                                   Wl10T, Wl11T, Wl20T, Wl21T, WnsT, WnvT, Wc);
  k_nodeemb<<<(NN*64+255)/256, 256, 0, stream>>>(attrs, Wc, pA, pB);
  k_feat_prep<<<NN*512/256, 256, 0, stream>>>(feats, fs16, fv16);
  k_node_pre2<<<dim3(NB64,13), 256, 0, stream>>>(fs16, fv16, WnsT, WnvT,
                                                 out_sc, (unsigned short*)upk, res_s, res_v);
  k_deg<<<(NE+255)/256, 256, 0, stream>>>(eidx, deg);
  k_scan<<<1, 256, 0, stream>>>(deg, offsets);
  k_fill<<<(NE+255)/256, 256, 0, stream>>>(eidx, offsets, cursor, elist);

  int tpw_blocks = (cap+63)/64;
  for (int c=0; c<nchunk; ++c){
    k_tpw<<<tpw_blocks, 256, 0, stream>>>(elist, eidx, ef, ea, pA, pB,
                                          Wr1, Wd1, Wd2, WTr2, WTr3, WTr4,
                                          offsets, c*npc, (c+1)*npc, cap,
                                          tpwp, ybuf, sndbuf, densbuf);
    k_gather<<<npc/4, 256, 0, stream>>>(tpwp, ybuf, sndbuf, densbuf, upk,
                                        offsets, c*npc, msg_s16, msg_v16, density);
  }

  k_post1<<<dim3(NB64,5), 256, 0, stream>>>(msg_s16, msg_v16, density, res_s, res_v,
                                            Wl10T, Wl11T, alphap, betap,
                                            scal16, gate16, vtmp16);
  k_post2<<<dim3(NB64,4), 256, 0, stream>>>(scal16, gate16, vtmp16,
                                            Wl20T, Wl21T, out_msg);
}

// Round 9
// 440.545 us; speedup vs baseline: 1.3200x; 1.0129x over previous
//
#include <hip/hip_runtime.h>
#include <hip/hip_bf16.h>
#include <math.h>

#define NN 10000
#define NE 160000
#define MUL 128
#define ADIM 10
#define RADF 8
#define HID 64
#define INV_SQRT3 0.57735026918962576f
#define NB64 157           // ceil(NN/64)

typedef __attribute__((ext_vector_type(8))) short bf16x8;
typedef __attribute__((ext_vector_type(4))) float f32x4;

__device__ __forceinline__ float silu_f(float x){ return x / (1.0f + __expf(-x)); }
__device__ __forceinline__ float sigmoid_f(float x){ return 1.0f / (1.0f + __expf(-x)); }
// legacy manual RNE (cold prep kernels)
__device__ __forceinline__ unsigned short f2b(float f){
  union{float f; unsigned u;} v; v.f=f;
  unsigned r = (v.u + 0x7fffu + ((v.u>>16)&1u))>>16;
  return (unsigned short)r;
}
// hot-path: native HW converts
__device__ __forceinline__ unsigned short f2bh(float f){
  __hip_bfloat16 h = __float2bfloat16(f);
  union{ __hip_bfloat16 h; unsigned short u; } v; v.h=h; return v.u;
}
__device__ __forceinline__ unsigned f2b2(float lo, float hi){
  float2 t; t.x=lo; t.y=hi;
  __hip_bfloat162 h2 = __float22bfloat162_rn(t);
  union{ __hip_bfloat162 h; unsigned u; } v; v.h=h2; return v.u;
}
__device__ __forceinline__ float b2f(unsigned short h){
  union{unsigned u; float f;} v; v.u = ((unsigned)h)<<16; return v.f;
}
__device__ __forceinline__ float b2f_lo(unsigned u){
  union{unsigned u; float f;} v; v.u = u<<16; return v.f;
}
__device__ __forceinline__ float b2f_hi(unsigned u){
  union{unsigned u; float f;} v; v.u = u & 0xffff0000u; return v.f;
}

// ---------------- per-node layer1 partials, packed {rad, den} float2 ----------------
__global__ __launch_bounds__(256) void k_nodeemb(
    const float* __restrict__ attrs, const float* __restrict__ Wc,
    float* __restrict__ pA, float* __restrict__ pB){
  int idx = blockIdx.x*256 + threadIdx.x;
  if (idx >= NN*64) return;
  int n = idx>>6, c = idx&63;
  float s0=0,s1=0,s2=0,s3=0;
  #pragma unroll
  for (int a=0;a<ADIM;a++){
    float x = attrs[n*ADIM+a];
    s0 += x*Wc[(0*ADIM+a)*64+c];
    s1 += x*Wc[(1*ADIM+a)*64+c];
    s2 += x*Wc[(2*ADIM+a)*64+c];
    s3 += x*Wc[(3*ADIM+a)*64+c];
  }
  pA[(size_t)n*128 + c*2 + 0] = s0;
  pA[(size_t)n*128 + c*2 + 1] = s2;
  pB[(size_t)n*128 + c*2 + 0] = s1;
  pB[(size_t)n*128 + c*2 + 1] = s3;
}

// ---------------- feat prep ----------------
__global__ __launch_bounds__(256) void k_feat_prep(
    const float* __restrict__ feats, unsigned short* __restrict__ fs16,
    unsigned short* __restrict__ fv16){
  int idx = blockIdx.x*256 + threadIdx.x;
  int n = idx >> 9, c = idx & 511;
  float v = feats[idx];
  if (c < 128) fs16[n*128 + c] = f2bh(v);
  else {
    int q = c - 128; int u = q/3; int i = q - 3*u;
    fv16[((size_t)n*3 + i)*128 + u] = f2bh(v);
  }
}

// ---------------- weight prep: transpose + bf16 cast (+ wcomb merged) ----------------
__global__ __launch_bounds__(256) void k_prep(
    const float* __restrict__ Wr2, const float* __restrict__ Wr3,
    const float* __restrict__ Wr4,
    const float* __restrict__ Wl10, const float* __restrict__ Wl11,
    const float* __restrict__ Wl20, const float* __restrict__ Wl21,
    const float* __restrict__ Wsk0, const float* __restrict__ Wup0, const float* __restrict__ Wres0,
    const float* __restrict__ Wsk1, const float* __restrict__ Wup1, const float* __restrict__ Wres1,
    const float* __restrict__ Wsrc, const float* __restrict__ Wtgt,
    const float* __restrict__ Wr1, const float* __restrict__ Wd1,
    unsigned short* __restrict__ WTr2, unsigned short* __restrict__ WTr3,
    unsigned short* __restrict__ WTr4,
    unsigned short* __restrict__ Wl10T, unsigned short* __restrict__ Wl11T,
    unsigned short* __restrict__ Wl20T, unsigned short* __restrict__ Wl21T,
    unsigned short* __restrict__ WnsT, unsigned short* __restrict__ WnvT,
    float* __restrict__ Wc){
  int idx = blockIdx.x*256 + threadIdx.x;
  if (idx < 4096){
    int j = idx; int n=j>>6, k=j&63;
    WTr2[j] = f2b(Wr2[k*64+n]);
  } else if (idx < 8192){
    int j = idx-4096; int n=j>>6, k=j&63;
    WTr3[j] = f2b(Wr3[k*64+n]);
  } else if (idx < 40960){
    int j = idx-8192; int n=j>>6, k=j&63;
    WTr4[j] = f2b(Wr4[k*512+n]);
  } else if (idx < 106496){
    int j = idx-40960; int n=j>>8, k=j&255;
    Wl10T[j] = f2b(Wl10[k*256+n]);
  } else if (idx < 139264){
    int j = idx-106496; int n=j>>8, k=j&255;
    Wl11T[j] = f2b(Wl11[k*128+n]);
  } else if (idx < 155648){
    int j = idx-139264; int n=j>>7, k=j&127;
    Wl20T[j] = f2b(Wl20[k*128+n]);
  } else if (idx < 172032){
    int j = idx-155648; int n=j>>7, k=j&127;
    Wl21T[j] = f2b(Wl21[k*128+n]);
  } else if (idx < 237568){
    int j = idx-172032; int n=j>>7, k=j&127;
    float v;
    if (n < 128)      v = Wsk0[k*128+n];
    else if (n < 256) v = Wup0[k*128+(n-128)];
    else              v = Wres0[k*256+(n-256)];
    WnsT[j] = f2b(v);
  } else if (idx < 286720){
    int j = idx-237568; int n=j>>7, k=j&127;
    float v;
    if (n < 128)      v = Wsk1[k*128+n];
    else if (n < 256) v = Wup1[k*128+(n-128)];
    else              v = Wres1[k*128+(n-256)];
    WnvT[j] = f2b(v);
  } else if (idx < 286976){
    int j = idx - 286720;      // wcomb: Wc[m][10][64]
    int m = j>>6, c = j&63;
    const float* WA = (m&1)? Wtgt : Wsrc;
    const float* WB = (m<2)? Wr1 : Wd1;
    int koff = (m&1)? 136 : 8;
    for (int a=0;a<ADIM;a++){
      float s=0.f;
      for (int k=0;k<128;k++) s += WA[a*128+k]*WB[(koff+k)*64+c];
      Wc[(m*ADIM+a)*64+c] = s;
    }
  }
}

// ---------------- K1: per-node precompute via MFMA ----------------
__global__ __launch_bounds__(256) void k_node_pre2(
    const unsigned short* __restrict__ fs16, const unsigned short* __restrict__ fv16,
    const unsigned short* __restrict__ WnsT, const unsigned short* __restrict__ WnvT,
    float* __restrict__ out_sc,
    unsigned short* __restrict__ upk16,
    float* __restrict__ res_s, float* __restrict__ res_v){
  __shared__ unsigned short fA[64][136];
  int nb = blockIdx.x*64;
  int c = blockIdx.y;
  int g, ntc;
  if (c < 4){ g=0; ntc=c; } else { g = 1 + (c-4)/3; ntc = (c-4)%3; }
  int tid = threadIdx.x;
  int w = tid>>6, l = tid&63, m0 = w*16, lr = l&15, lg = l>>4;
  for (int idx=tid; idx<64*16; idx+=256){
    int row = idx>>4, s8 = idx&15;
    int n = min(nb+row, NN-1);
    const unsigned short* src = (g==0) ? &fs16[(size_t)n*128 + s8*8]
                                       : &fv16[((size_t)n*3 + (g-1))*128 + s8*8];
    *(uint4*)&fA[row][s8*8] = *(const uint4*)src;
  }
  __syncthreads();
  const unsigned short* WT = ((g==0)? WnsT : WnvT) + (size_t)ntc*128*128;
  f32x4 acc[8];
  #pragma unroll
  for (int t=0;t<8;t++) acc[t]=(f32x4)(0.f);
  #pragma unroll
  for (int kb=0;kb<4;kb++){
    bf16x8 a = *(const bf16x8*)&fA[m0+lr][kb*32 + lg*8];
    #pragma unroll
    for (int t=0;t<8;t++){
      bf16x8 b = *(const bf16x8*)&WT[(size_t)(t*16+lr)*128 + kb*32 + lg*8];
      acc[t] = __builtin_amdgcn_mfma_f32_16x16x32_bf16(a, b, acc[t], 0,0,0);
    }
  }
  #pragma unroll
  for (int t=0;t<8;t++){
    #pragma unroll
    for (int r=0;r<4;r++){
      int col = (ntc*8+t)*16 + lr;
      int row = m0 + lg*4 + r;
      int n = nb + row;
      if (n < NN){
        float v = acc[t][r];
        if (g==0){
          if (col < 128)      out_sc[(size_t)n*512 + col] = v;
          else if (col < 256){
            int cc = col-128;
            upk16[(size_t)n*512 + (cc&63)*8 + (cc>>6)] = f2bh(v);
          } else              res_s[(size_t)n*256 + col-256] = v;
        } else {
          int i = g-1;
          if (col < 128)      out_sc[(size_t)n*512 + 128 + col*3 + i] = v;
          else if (col < 256){
            int cc = col-128;
            upk16[(size_t)n*512 + (cc&63)*8 + (1+i)*2 + (cc>>6)] = f2bh(v);
          } else              res_v[((size_t)n*3+i)*128 + col-256] = v;
        }
      }
    }
  }
}

// ---------------- CSR build ----------------
__global__ __launch_bounds__(256) void k_deg(const int* __restrict__ eidx, int* __restrict__ deg){
  int i = blockIdx.x*256+threadIdx.x;
  if (i<NE) atomicAdd(&deg[eidx[2*i+1]],1);
}
__global__ __launch_bounds__(256) void k_scan(const int* __restrict__ deg, int* __restrict__ offsets){
  __shared__ int part[256];
  int t = threadIdx.x; int base = t*40;
  int s=0;
  for (int k=0;k<40;k++){ int idx=base+k; if (idx<NN) s+=deg[idx]; }
  part[t]=s; __syncthreads();
  if (t==0){ int run=0; for (int i=0;i<256;i++){ int v=part[i]; part[i]=run; run+=v; } }
  __syncthreads();
  int run = part[t];
  for (int k=0;k<40;k++){
    int idx=base+k;
    if (idx<=NN) offsets[idx]=run;
    if (idx<NN) run+=deg[idx];
  }
}
__global__ __launch_bounds__(256) void k_fill(const int* __restrict__ eidx, const int* __restrict__ offsets,
                                              int* __restrict__ cursor, int* __restrict__ elist){
  int i = blockIdx.x*256+threadIdx.x;
  if (i<NE){ int r = eidx[2*i+1]; int p = atomicAdd(&cursor[r],1); elist[offsets[r]+p]=i; }
}

// ---------------- K2: edge MLP -> tpwp [edge][lane][4 u32] (direct reg->global) ------
__global__ __launch_bounds__(256) void k_tpw(
    const int* __restrict__ elist, const int* __restrict__ eidx,
    const float* __restrict__ ef, const float* __restrict__ ea,
    const float* __restrict__ pA, const float* __restrict__ pB,
    const float* __restrict__ Wr1, const float* __restrict__ Wd1, const float* __restrict__ Wd2,
    const unsigned short* __restrict__ WTr2, const unsigned short* __restrict__ WTr3,
    const unsigned short* __restrict__ WTr4,
    const int* __restrict__ offsets, int nstart, int nend, int cap,
    unsigned* __restrict__ tpwp, float4* __restrict__ ybuf,
    int* __restrict__ sndbuf, float* __restrict__ densbuf){
  __shared__ unsigned short hA[64][72];
  __shared__ unsigned short hB[64][72];
  __shared__ float efs[64][8];
  __shared__ int s_snd[64], s_rcv[64];
  int ebase = offsets[nstart];
  int eend  = min(offsets[nend], ebase + cap);
  int i0 = ebase + blockIdx.x*64;
  if (i0 >= eend) return;
  int nrows = min(64, eend - i0);
  int tid = threadIdx.x;
  int w = tid>>6, l = tid&63, m0 = w*16, lr = l&15, lg = l>>4;
  if (tid < 64){
    int ii = min(i0 + tid, eend-1);
    int e = elist[ii];
    int sn = eidx[2*e], rc = eidx[2*e+1];
    s_snd[tid]=sn; s_rcv[tid]=rc;
    if (tid < nrows){
      int li = i0 - ebase + tid;
      sndbuf[li] = sn;
      ybuf[li] = ((const float4*)ea)[e];
    }
  }
  if (tid < 128){
    int r = tid>>1, hf = tid&1;
    int e = elist[min(i0+r, eend-1)];
    *(float4*)&efs[r][hf*4] = *(const float4*)&ef[(size_t)e*8 + hf*4];
  }
  __syncthreads();
  // ---- layer1 (VALU, f32), packed node partials ----
  {
    float wr[8], wd[8];
    #pragma unroll
    for (int k=0;k<8;k++){ wr[k]=Wr1[k*64+l]; wd[k]=Wd1[k*64+l]; }
    float wd2c = Wd2[l];
    #pragma unroll
    for (int j=0;j<16;j++){
      int r = m0+j;
      int sn = s_snd[r], rc = s_rcv[r];
      float2 av = *(const float2*)&pA[(size_t)sn*128 + l*2];
      float2 bv = *(const float2*)&pB[(size_t)rc*128 + l*2];
      float h  = av.x + bv.x;
      float hd = av.y + bv.y;
      #pragma unroll
      for (int k=0;k<8;k++){ float ek=efs[r][k]; h += ek*wr[k]; hd += ek*wd[k]; }
      hA[r][l] = f2bh(silu_f(h));
      float sv = silu_f(hd)*wd2c;
      #pragma unroll
      for (int m=32;m;m>>=1) sv += __shfl_xor(sv, m);
      if (l==0 && r < nrows) densbuf[i0 - ebase + r] = tanhf(sv*sv);
    }
  }
  // ---- layer2: hA -> hB (wave-private rows, no barrier) ----
  f32x4 acc[4];
  #pragma unroll
  for (int nt=0;nt<4;nt++) acc[nt]=(f32x4)(0.f);
  #pragma unroll
  for (int kb=0;kb<2;kb++){
    bf16x8 a = *(const bf16x8*)&hA[m0+lr][kb*32 + lg*8];
    #pragma unroll
    for (int nt=0;nt<4;nt++){
      bf16x8 b = *(const bf16x8*)&WTr2[(nt*16+lr)*64 + kb*32 + lg*8];
      acc[nt] = __builtin_amdgcn_mfma_f32_16x16x32_bf16(a, b, acc[nt], 0,0,0);
    }
  }
  #pragma unroll
  for (int nt=0;nt<4;nt++)
    #pragma unroll
    for (int r=0;r<4;r++)
      hB[m0+lg*4+r][nt*16+lr] = f2bh(silu_f(acc[nt][r]));
  // ---- layer3: hB -> hA ----
  #pragma unroll
  for (int nt=0;nt<4;nt++) acc[nt]=(f32x4)(0.f);
  #pragma unroll
  for (int kb=0;kb<2;kb++){
    bf16x8 a = *(const bf16x8*)&hB[m0+lr][kb*32 + lg*8];
    #pragma unroll
    for (int nt=0;nt<4;nt++){
      bf16x8 b = *(const bf16x8*)&WTr3[(nt*16+lr)*64 + kb*32 + lg*8];
      acc[nt] = __builtin_amdgcn_mfma_f32_16x16x32_bf16(a, b, acc[nt], 0,0,0);
    }
  }
  #pragma unroll
  for (int nt=0;nt<4;nt++)
    #pragma unroll
    for (int r=0;r<4;r++)
      hA[m0+lg*4+r][nt*16+lr] = f2bh(silu_f(acc[nt][r]));
  // ---- layer4: direct reg->global, [edge][lane c][G] packed u32, 16B stores ----
  int erow0 = i0 - ebase;
  #pragma unroll
  for (int nt=0; nt<4; nt++){
    unsigned pvv[4][4];   // [r][G]
    #pragma unroll
    for (int G=0; G<4; G++){
      f32x4 aE=(f32x4)(0.f), aO=(f32x4)(0.f);
      #pragma unroll
      for (int kb=0; kb<2; kb++){
        bf16x8 a  = *(const bf16x8*)&hA[m0+lr][kb*32 + lg*8];
        bf16x8 bE = *(const bf16x8*)&WTr4[((2*G)*64+nt*16+lr)*64 + kb*32 + lg*8];
        bf16x8 bO = *(const bf16x8*)&WTr4[((2*G+1)*64+nt*16+lr)*64 + kb*32 + lg*8];
        aE = __builtin_amdgcn_mfma_f32_16x16x32_bf16(a, bE, aE, 0,0,0);
        aO = __builtin_amdgcn_mfma_f32_16x16x32_bf16(a, bO, aO, 0,0,0);
      }
      #pragma unroll
      for (int r=0;r<4;r++)
        pvv[r][G] = f2b2(aE[r], aO[r]);
    }
    #pragma unroll
    for (int r=0;r<4;r++){
      int row = m0 + lg*4 + r;
      if (row < nrows)
        *(uint4*)&tpwp[(size_t)(erow0+row)*256 + (nt*16+lr)*4] = *(uint4*)&pvv[r][0];
    }
  }
}

// ---------------- K3: CSR gather — 2 waves per node, LDS combine ----------------
__global__ __launch_bounds__(256) void k_gather(
    const unsigned* __restrict__ tpwp, const float4* __restrict__ ybuf,
    const int* __restrict__ sndbuf, const float* __restrict__ densbuf,
    const uint4* __restrict__ upk4,
    const int* __restrict__ offsets, int nstart,
    unsigned short* __restrict__ msg_s16, unsigned short* __restrict__ msg_v16,
    float* __restrict__ density){
  __shared__ float part[2][1024];
  __shared__ float pden[2];
  int w = threadIdx.x>>6, l = threadIdx.x&63;
  int pairIdx = w>>1, half = w&1;
  int n = nstart + blockIdx.x*2 + pairIdx;
  int ebase = offsets[nstart];
  int s0 = offsets[n], s1 = offsets[n+1];
  float mA0=0,mA1=0,mD0=0,mD1=0;
  float mB00=0,mB01=0,mB10=0,mB11=0,mB20=0,mB21=0;
  float mC00=0,mC01=0,mC10=0,mC11=0,mC20=0,mC21=0;
  float dsum=0;
  for (int i=s0+half; i<s1; i+=2){
    int li = i - ebase;
    int sn = sndbuf[li];
    float4 y = ybuf[li];
    dsum += densbuf[li];
    uint4 tq = *(const uint4*)&tpwp[(size_t)li*256 + l*4];
    uint4 uq = upk4[(size_t)sn*64 + l];
    float wA0=b2f_lo(tq.x), wA1=b2f_hi(tq.x);
    float wB0=b2f_lo(tq.y), wB1=b2f_hi(tq.y);
    float wC0=b2f_lo(tq.z), wC1=b2f_hi(tq.z);
    float wD0=b2f_lo(tq.w), wD1=b2f_hi(tq.w);
    float xs0=b2f_lo(uq.x), xs1=b2f_hi(uq.x);
    float xv00=b2f_lo(uq.y), xv01=b2f_hi(uq.y);
    float xv10=b2f_lo(uq.z), xv11=b2f_hi(uq.z);
    float xv20=b2f_lo(uq.w), xv21=b2f_hi(uq.w);
    mA0 += wA0*xs0*y.x; mA1 += wA1*xs1*y.x;
    float dot0 = xv00*y.y + xv10*y.z + xv20*y.w;
    float dot1 = xv01*y.y + xv11*y.z + xv21*y.w;
    mD0 += wD0*dot0; mD1 += wD1*dot1;
    float b0 = wB0*xs0, b1 = wB1*xs1;
    mB00 += b0*y.y; mB01 += b1*y.y;
    mB10 += b0*y.z; mB11 += b1*y.z;
    mB20 += b0*y.w; mB21 += b1*y.w;
    float c0 = wC0*y.x, c1 = wC1*y.x;
    mC00 += c0*xv00; mC01 += c1*xv01;
    mC10 += c0*xv10; mC11 += c1*xv11;
    mC20 += c0*xv20; mC21 += c1*xv21;
  }
  if (half==1){
    float* P = part[pairIdx];
    P[0*64+l]=mA0;  P[1*64+l]=mA1;  P[2*64+l]=mD0;  P[3*64+l]=mD1;
    P[4*64+l]=mB00; P[5*64+l]=mB01; P[6*64+l]=mB10; P[7*64+l]=mB11;
    P[8*64+l]=mB20; P[9*64+l]=mB21; P[10*64+l]=mC00; P[11*64+l]=mC01;
    P[12*64+l]=mC10; P[13*64+l]=mC11; P[14*64+l]=mC20; P[15*64+l]=mC21;
    if (l==0) pden[pairIdx]=dsum;
  }
  __syncthreads();
  if (half==0){
    const float* P = part[pairIdx];
    mA0+=P[0*64+l];  mA1+=P[1*64+l];  mD0+=P[2*64+l];  mD1+=P[3*64+l];
    mB00+=P[4*64+l]; mB01+=P[5*64+l]; mB10+=P[6*64+l]; mB11+=P[7*64+l];
    mB20+=P[8*64+l]; mB21+=P[9*64+l]; mC00+=P[10*64+l]; mC01+=P[11*64+l];
    mC10+=P[12*64+l]; mC11+=P[13*64+l]; mC20+=P[14*64+l]; mC21+=P[15*64+l];
    dsum += pden[pairIdx];
    unsigned short* ms = msg_s16 + (size_t)n*256;
    ms[l]=f2bh(mA0); ms[64+l]=f2bh(mA1);
    ms[128+l]=f2bh(mD0*INV_SQRT3); ms[192+l]=f2bh(mD1*INV_SQRT3);
    unsigned short* mv = msg_v16 + (size_t)n*768;
    mv[l]=f2bh(mB00);     mv[64+l]=f2bh(mB01);  mv[128+l]=f2bh(mC00); mv[192+l]=f2bh(mC01);
    mv[256+l]=f2bh(mB10); mv[320+l]=f2bh(mB11); mv[384+l]=f2bh(mC10); mv[448+l]=f2bh(mC11);
    mv[512+l]=f2bh(mB20); mv[576+l]=f2bh(mB21); mv[640+l]=f2bh(mC20); mv[704+l]=f2bh(mC21);
    if (l==0) density[n]=dsum;
  }
}

// ---------------- K4a: lin1 for all 5 N=128 chunks. grid (NB64, 5) ----------------
__global__ __launch_bounds__(256) void k_post1(
    const unsigned short* __restrict__ msg_s16, const unsigned short* __restrict__ msg_v16,
    const float* __restrict__ density,
    const float* __restrict__ res_s, const float* __restrict__ res_v,
    const unsigned short* __restrict__ Wl10T, const unsigned short* __restrict__ Wl11T,
    const float* __restrict__ alphap, const float* __restrict__ betap,
    unsigned short* __restrict__ scal16, unsigned short* __restrict__ gate16,
    unsigned short* __restrict__ vtmp16){
  __shared__ unsigned short sm[64][264];
  __shared__ float sden[64];
  int nb = blockIdx.x*64, y = blockIdx.y;
  int tid = threadIdx.x;
  int w = tid>>6, l = tid&63, m0 = w*16, lr = l&15, lg = l>>4;
  for (int idx=tid; idx<64*32; idx+=256){
    int row = idx>>5, s8 = idx&31;
    int n = min(nb+row, NN-1);
    const unsigned short* src = (y<2)? &msg_s16[(size_t)n*256 + s8*8]
                                     : &msg_v16[(size_t)n*768 + (y-2)*256 + s8*8];
    *(uint4*)&sm[row][s8*8] = *(const uint4*)src;
  }
  if (tid < 64){
    int n = min(nb+tid, NN-1);
    sden[tid] = density[n]*betap[0] + alphap[0]*20.0f;
  }
  __syncthreads();
  const unsigned short* BT = (y<2)? (Wl10T + (size_t)y*128*256) : Wl11T;
  f32x4 acc[8];
  #pragma unroll
  for (int t=0;t<8;t++) acc[t]=(f32x4)(0.f);
  for (int kb=0;kb<8;kb++){
    bf16x8 a = *(const bf16x8*)&sm[m0+lr][kb*32 + lg*8];
    #pragma unroll
    for (int t=0;t<8;t++){
      bf16x8 b = *(const bf16x8*)&BT[(size_t)(t*16+lr)*256 + kb*32 + lg*8];
      acc[t] = __builtin_amdgcn_mfma_f32_16x16x32_bf16(a, b, acc[t], 0,0,0);
    }
  }
  #pragma unroll
  for (int t=0;t<8;t++){
    #pragma unroll
    for (int r=0;r<4;r++){
      int col = t*16+lr;
      int row = m0 + lg*4 + r;
      int n = nb + row;
      if (n < NN){
        float v = acc[t][r]/sden[row];
        if (y==0){
          v += res_s[(size_t)n*256 + col];
          scal16[(size_t)n*128 + col] = f2bh(silu_f(v));
        } else if (y==1){
          v += res_s[(size_t)n*256 + 128 + col];
          gate16[(size_t)n*128 + col] = f2bh(sigmoid_f(v));
        } else {
          int i = y-2;
          v += res_v[((size_t)n*3+i)*128 + col];
          vtmp16[((size_t)i*NN + n)*128 + col] = f2bh(v);
        }
      }
    }
  }
}

// ---------------- K4b: lin2 for 4 output components. grid (NB64, 4) ----------------
__global__ __launch_bounds__(256) void k_post2(
    const unsigned short* __restrict__ scal16, const unsigned short* __restrict__ gate16,
    const unsigned short* __restrict__ vtmp16,
    const unsigned short* __restrict__ Wl20T, const unsigned short* __restrict__ Wl21T,
    float* __restrict__ out_msg){
  __shared__ unsigned short sA[64][136];
  int nb = blockIdx.x*64, y = blockIdx.y;
  int tid = threadIdx.x;
  int w = tid>>6, l = tid&63, m0 = w*16, lr = l&15, lg = l>>4;
  for (int idx=tid; idx<64*16; idx+=256){
    int row = idx>>4, s8 = idx&15;
    int n = min(nb+row, NN-1);
    if (y==0){
      *(uint4*)&sA[row][s8*8] = *(const uint4*)&scal16[(size_t)n*128 + s8*8];
    } else {
      int i = y-1;
      uint4 va = *(const uint4*)&vtmp16[((size_t)i*NN + n)*128 + s8*8];
      uint4 vg = *(const uint4*)&gate16[(size_t)n*128 + s8*8];
      const unsigned short* pa = (const unsigned short*)&va;
      const unsigned short* pg = (const unsigned short*)&vg;
      unsigned short o[8];
      #pragma unroll
      for (int j=0;j<8;j++) o[j] = f2bh(b2f(pa[j])*b2f(pg[j]));
      *(uint4*)&sA[row][s8*8] = *(const uint4*)o;
    }
  }
  __syncthreads();
  const unsigned short* BT = (y==0)? Wl20T : Wl21T;
  f32x4 acc[8];
  #pragma unroll
  for (int t=0;t<8;t++) acc[t]=(f32x4)(0.f);
  #pragma unroll
  for (int kb=0;kb<4;kb++){
    bf16x8 a = *(const bf16x8*)&sA[m0+lr][kb*32 + lg*8];
    #pragma unroll
    for (int t=0;t<8;t++){
      bf16x8 b = *(const bf16x8*)&BT[(size_t)(t*16+lr)*128 + kb*32 + lg*8];
      acc[t] = __builtin_amdgcn_mfma_f32_16x16x32_bf16(a, b, acc[t], 0,0,0);
    }
  }
  #pragma unroll
  for (int t=0;t<8;t++){
    #pragma unroll
    for (int r=0;r<4;r++){
      int col = t*16+lr;
      int n = nb + m0 + lg*4 + r;
      if (n < NN) out_msg[(size_t)n*512 + col*4 + y] = acc[t][r];
    }
  }
}

extern "C" void kernel_launch(void* const* d_in, const int* in_sizes, int n_in,
                              void* d_out, int out_size, void* d_ws, size_t ws_size,
                              hipStream_t stream){
  (void)in_sizes; (void)n_in; (void)out_size;
  const float* attrs = (const float*)d_in[0];
  const float* feats = (const float*)d_in[1];
  const float* ea    = (const float*)d_in[2];
  const float* ef    = (const float*)d_in[3];
  const float* Wsrc  = (const float*)d_in[4];
  const float* Wtgt  = (const float*)d_in[5];
  const float* Wup0  = (const float*)d_in[6];
  const float* Wup1  = (const float*)d_in[7];
  const float* Wsk0  = (const float*)d_in[8];
  const float* Wsk1  = (const float*)d_in[9];
  const float* Wres0 = (const float*)d_in[10];
  const float* Wres1 = (const float*)d_in[11];
  const float* Wl10  = (const float*)d_in[12];
  const float* Wl11  = (const float*)d_in[13];
  const float* Wl20  = (const float*)d_in[14];
  const float* Wl21  = (const float*)d_in[15];
  const float* Wr1   = (const float*)d_in[16];
  const float* Wr2   = (const float*)d_in[17];
  const float* Wr3   = (const float*)d_in[18];
  const float* Wr4   = (const float*)d_in[19];
  const float* Wd1   = (const float*)d_in[20];
  const float* Wd2   = (const float*)d_in[21];
  const float* alphap= (const float*)d_in[22];
  const float* betap = (const float*)d_in[23];
  const int*   eidx  = (const int*)d_in[24];

  const size_t fixed_bytes =
      (size_t)NN*(512 + 1536 + 1024 + 1536 + 4 + 1024 + 256 + 768 + 512 + 512 + 256) +
      (size_t)286976*2 + 4*ADIM*64*4 +
      (10240+10240+10256)*4 + (size_t)NE*4 + 64*256;
  int nchunk, npc, cap;
  if (fixed_bytes + (size_t)NE*1048 + 65536 <= ws_size){ nchunk=1; npc=NN;   cap=NE;    }
  else if (fixed_bytes + 81920ULL*1048 + 65536 <= ws_size){ nchunk=2; npc=5000; cap=81920; }
  else { nchunk=4; npc=2500; cap=44032; }

  char* p = (char*)d_ws;
  auto alloc = [&](size_t bytes)->char*{ char* r=p; p += (bytes+255)&~(size_t)255; return r; };
  unsigned* tpwp  = (unsigned*)alloc((size_t)cap*256*4);
  unsigned short* msg_s16 = (unsigned short*)alloc((size_t)NN*256*2);
  unsigned short* msg_v16 = (unsigned short*)alloc((size_t)NN*768*2);
  float*  res_s   = (float*)alloc((size_t)NN*256*4);
  float*  res_v   = (float*)alloc((size_t)NN*384*4);
  float*  density = (float*)alloc((size_t)NN*4);
  float4* ybuf    = (float4*)alloc((size_t)cap*16);
  float*  densbuf = (float*)alloc((size_t)cap*4);
  int*    sndbuf  = (int*)alloc((size_t)cap*4);
  uint4*  upk     = (uint4*)alloc((size_t)NN*64*16);
  unsigned short* fs16 = (unsigned short*)alloc((size_t)NN*128*2);
  unsigned short* fv16 = (unsigned short*)alloc((size_t)NN*384*2);
  float* pA = (float*)alloc((size_t)NN*128*4);
  float* pB = (float*)alloc((size_t)NN*128*4);
  float* Wc  = (float*)alloc(4*ADIM*64*4);
  unsigned short* gate16 = (unsigned short*)alloc((size_t)NN*128*2);
  unsigned short* WTr2 = (unsigned short*)alloc(4096*2);
  unsigned short* WTr3 = (unsigned short*)alloc(4096*2);
  unsigned short* WTr4 = (unsigned short*)alloc(32768*2);
  unsigned short* Wl10T = (unsigned short*)alloc(65536*2);
  unsigned short* Wl11T = (unsigned short*)alloc(32768*2);
  unsigned short* Wl20T = (unsigned short*)alloc(16384*2);
  unsigned short* Wl21T = (unsigned short*)alloc(16384*2);
  unsigned short* WnsT  = (unsigned short*)alloc(65536*2);
  unsigned short* WnvT  = (unsigned short*)alloc(49152*2);
  int* deg     = (int*)alloc(10240*4);
  int* cursor  = (int*)alloc(10240*4);
  int* offsets = (int*)alloc(10256*4);
  int* elist   = (int*)alloc((size_t)NE*4);

  unsigned short* scal16 = fs16;   // NN*128, fs16 dead after k_node_pre2
  unsigned short* vtmp16 = fv16;   // 3*NN*128, fv16 dead after k_node_pre2

  float* out_msg = (float*)d_out;               // NN*512
  float* out_sc  = out_msg + (size_t)NN*512;    // NN*512

  hipMemsetAsync(deg, 0, 2*10240*sizeof(int), stream);

  k_prep<<<1121, 256, 0, stream>>>(Wr2, Wr3, Wr4, Wl10, Wl11, Wl20, Wl21,
                                   Wsk0, Wup0, Wres0, Wsk1, Wup1, Wres1,
                                   Wsrc, Wtgt, Wr1, Wd1,
                                   WTr2, WTr3, WTr4,
                                   Wl10T, Wl11T, Wl20T, Wl21T, WnsT, WnvT, Wc);
  k_nodeemb<<<(NN*64+255)/256, 256, 0, stream>>>(attrs, Wc, pA, pB);
  k_feat_prep<<<NN*512/256, 256, 0, stream>>>(feats, fs16, fv16);
  k_node_pre2<<<dim3(NB64,13), 256, 0, stream>>>(fs16, fv16, WnsT, WnvT,
                                                 out_sc, (unsigned short*)upk, res_s, res_v);
  k_deg<<<(NE+255)/256, 256, 0, stream>>>(eidx, deg);
  k_scan<<<1, 256, 0, stream>>>(deg, offsets);
  k_fill<<<(NE+255)/256, 256, 0, stream>>>(eidx, offsets, cursor, elist);

  int tpw_blocks = (cap+63)/64;
  for (int c=0; c<nchunk; ++c){
    k_tpw<<<tpw_blocks, 256, 0, stream>>>(elist, eidx, ef, ea, pA, pB,
                                          Wr1, Wd1, Wd2, WTr2, WTr3, WTr4,
                                          offsets, c*npc, (c+1)*npc, cap,
                                          tpwp, ybuf, sndbuf, densbuf);
    k_gather<<<npc/2, 256, 0, stream>>>(tpwp, ybuf, sndbuf, densbuf, upk,
                                        offsets, c*npc, msg_s16, msg_v16, density);
  }

  k_post1<<<dim3(NB64,5), 256, 0, stream>>>(msg_s16, msg_v16, density, res_s, res_v,
                                            Wl10T, Wl11T, alphap, betap,
                                            scal16, gate16, vtmp16);
  k_post2<<<dim3(NB64,4), 256, 0, stream>>>(scal16, gate16, vtmp16,
                                            Wl20T, Wl21T, out_msg);
}